// Round 1
// baseline (1124.180 us; speedup 1.0000x reference)
//
#include <hip/hip_runtime.h>
#include <cstddef>
#include <cstdint>

// DiffMLA attention, MI355X baseline.
// Pipeline: bf16 conversions -> MFMA GEMMs (64x64 tile) with pack epilogues ->
// RMS/RoPE/lambda fp32 kernels -> flash-style MFMA attention -> combine -> out GEMM.

namespace {

constexpr int kBatch = 2, kLen = 2048, kDim = 2048, kNH = 16, kDH = 128, kDHR = 64, kDC = 1024;
constexpr float kScale = 0.07216878364870323f;  // 1/sqrt(192)

typedef __bf16 bf16x8 __attribute__((ext_vector_type(8)));
typedef float f32x4 __attribute__((ext_vector_type(4)));

__device__ __forceinline__ unsigned short f2bf(float f) {
  union { float f; unsigned int u; } v; v.f = f;
  unsigned int r = v.u + 0x7FFFu + ((v.u >> 16) & 1u);
  return (unsigned short)(r >> 16);
}
__device__ __forceinline__ float bf2f(unsigned short h) {
  union { unsigned int u; float f; } v; v.u = ((unsigned int)h) << 16;
  return v.f;
}
__device__ __forceinline__ f32x4 mfma16(bf16x8 a, bf16x8 b, f32x4 c) {
  return __builtin_amdgcn_mfma_f32_16x16x32_bf16(a, b, c, 0, 0, 0);
}

// ---------------- elementwise convert f32 -> bf16 (x4 vectorized) ----------------
__global__ __launch_bounds__(256) void conv_bf16_kernel(const float* __restrict__ in,
                                                        unsigned short* __restrict__ out, int n4) {
  int e = blockIdx.x * 256 + threadIdx.x;
  if (e >= n4) return;
  float4 v = reinterpret_cast<const float4*>(in)[e];
  uint2 pk;
  pk.x = (unsigned int)f2bf(v.x) | ((unsigned int)f2bf(v.y) << 16);
  pk.y = (unsigned int)f2bf(v.z) | ((unsigned int)f2bf(v.w) << 16);
  reinterpret_cast<uint2*>(out)[e] = pk;
}

// ------------- transpose+convert: in (K x N) f32 -> out (N x K) bf16 -------------
__global__ __launch_bounds__(256) void transpose_conv_kernel(const float* __restrict__ in,
                                                             unsigned short* __restrict__ out,
                                                             int K, int N) {
  __shared__ float t[32][33];
  int n0 = blockIdx.x * 32, k0 = blockIdx.y * 32;
  int tx = threadIdx.x & 31, ty = threadIdx.x >> 5;
#pragma unroll
  for (int i = 0; i < 4; i++) t[ty + i * 8][tx] = in[(size_t)(k0 + ty + i * 8) * N + n0 + tx];
  __syncthreads();
#pragma unroll
  for (int i = 0; i < 4; i++)
    out[(size_t)(n0 + ty + i * 8) * K + k0 + tx] = f2bf(t[tx][ty + i * 8]);
}

// ---------------- generic MFMA GEMM: C(MxN) = A(MxK) * Bt(NxK)^T ----------------
// MODE 0: dst = fp32 row-major C
// MODE 1: dst = k_all bf16, col=(h*128+d) -> [((b*16+h)*2048+l)*192 + d]
// MODE 2: dst = v_allT bf16, col=(h*128+d) -> [((b*16+h)*128+d)*2048 + l]
// MODE 3: dst = q_all bf16, col=(h2*128+d) -> [((b*32+h2)*2048+l)*192 + d]
template <int MODE>
__global__ __launch_bounds__(256) void gemm_bt_kernel(const unsigned short* __restrict__ A,
                                                      const unsigned short* __restrict__ Bt,
                                                      void* __restrict__ dst, int M, int N, int K) {
  // rows padded to 40 elems (80 B): fragment ds_read_b128s land <=2-way per bank (free).
  __shared__ unsigned short lds_a[64 * 40];
  __shared__ unsigned short lds_b[64 * 40];
  int tid = threadIdx.x;
  int lane = tid & 63, w = tid >> 6;
  int quad = lane >> 4, l16 = lane & 15;
  int wr = w >> 1, wc = w & 1;
  int nbase = blockIdx.x * 64, mbase = blockIdx.y * 64;
  f32x4 acc[2][2] = {};
  int srow = tid >> 2;
  int skoff = (tid & 3) * 8;
  const size_t a_off = (size_t)(mbase + srow) * K + skoff;
  const size_t b_off = (size_t)(nbase + srow) * K + skoff;
  for (int k0 = 0; k0 < K; k0 += 32) {
    __syncthreads();
    *reinterpret_cast<bf16x8*>(&lds_a[srow * 40 + skoff]) =
        *reinterpret_cast<const bf16x8*>(&A[a_off + k0]);
    *reinterpret_cast<bf16x8*>(&lds_b[srow * 40 + skoff]) =
        *reinterpret_cast<const bf16x8*>(&Bt[b_off + k0]);
    __syncthreads();
    bf16x8 af0 = *reinterpret_cast<const bf16x8*>(&lds_a[(wr * 32 + l16) * 40 + quad * 8]);
    bf16x8 af1 = *reinterpret_cast<const bf16x8*>(&lds_a[(wr * 32 + 16 + l16) * 40 + quad * 8]);
    bf16x8 bf0 = *reinterpret_cast<const bf16x8*>(&lds_b[(wc * 32 + l16) * 40 + quad * 8]);
    bf16x8 bf1 = *reinterpret_cast<const bf16x8*>(&lds_b[(wc * 32 + 16 + l16) * 40 + quad * 8]);
    acc[0][0] = mfma16(af0, bf0, acc[0][0]);
    acc[0][1] = mfma16(af0, bf1, acc[0][1]);
    acc[1][0] = mfma16(af1, bf0, acc[1][0]);
    acc[1][1] = mfma16(af1, bf1, acc[1][1]);
  }
#pragma unroll
  for (int mt = 0; mt < 2; mt++)
#pragma unroll
    for (int nt = 0; nt < 2; nt++)
#pragma unroll
      for (int r = 0; r < 4; r++) {
        int gr = mbase + wr * 32 + mt * 16 + quad * 4 + r;
        int gc = nbase + wc * 32 + nt * 16 + l16;
        float v = acc[mt][nt][r];
        if (MODE == 0) {
          reinterpret_cast<float*>(dst)[(size_t)gr * N + gc] = v;
        } else {
          int bb = gr >> 11, l = gr & 2047;
          unsigned short hv = f2bf(v);
          unsigned short* o = reinterpret_cast<unsigned short*>(dst);
          if (MODE == 1) {
            int h = gc >> 7, d2 = gc & 127;
            o[((size_t)((bb * 16 + h) * 2048 + l)) * 192 + d2] = hv;
          } else if (MODE == 2) {
            int h = gc >> 7, d2 = gc & 127;
            o[((size_t)((bb * 16 + h) * 128 + d2)) * 2048 + l] = hv;
          } else {
            int h2 = gc >> 7, d2 = gc & 127;
            o[((size_t)((bb * 32 + h2) * 2048 + l)) * 192 + d2] = hv;
          }
        }
      }
}

// ---------------- RMS norm: in fp32 (rows x 1024) -> out bf16 ----------------
__global__ __launch_bounds__(256) void rms_kernel(const float* __restrict__ in,
                                                  const float* __restrict__ w,
                                                  unsigned short* __restrict__ out) {
  int row = blockIdx.x, tid = threadIdx.x;
  float4 v = reinterpret_cast<const float4*>(in + (size_t)row * kDC)[tid];
  float ss = v.x * v.x + v.y * v.y + v.z * v.z + v.w * v.w;
  ss += __shfl_xor(ss, 1); ss += __shfl_xor(ss, 2); ss += __shfl_xor(ss, 4);
  ss += __shfl_xor(ss, 8); ss += __shfl_xor(ss, 16); ss += __shfl_xor(ss, 32);
  __shared__ float red[4];
  if ((tid & 63) == 0) red[tid >> 6] = ss;
  __syncthreads();
  float tot = red[0] + red[1] + red[2] + red[3];
  float rs = rsqrtf(tot * (1.0f / kDC) + 1e-6f);
  float4 wv = reinterpret_cast<const float4*>(w)[tid];
  uint2 pk;
  pk.x = (unsigned int)f2bf(v.x * rs * wv.x) | ((unsigned int)f2bf(v.y * rs * wv.y) << 16);
  pk.y = (unsigned int)f2bf(v.z * rs * wv.z) | ((unsigned int)f2bf(v.w * rs * wv.w) << 16);
  reinterpret_cast<uint2*>(out)[(size_t)row * 256 + tid] = pk;
}

// ---------------- RoPE helpers ----------------
__device__ __forceinline__ float rope_val(float x1, float x2, int j, int l) {
  int i = j & 31;
  float inv_freq = powf(10000.0f, -(float)i * (1.0f / 32.0f));
  float ang = (float)l * inv_freq;
  float cv = cosf(ang), sv = sinf(ang);
  float rot = (j < 32) ? -x2 : x2;
  return x1 * cv + rot * sv;
}

// q_r: tmp (4096 x 2048 fp32, col = h2*64+j) -> q_all[..., 128+j]
__global__ __launch_bounds__(256) void rope_q_kernel(const float* __restrict__ qr_raw,
                                                     unsigned short* __restrict__ q_all) {
  size_t e = (size_t)blockIdx.x * 256 + threadIdx.x;  // 4096*32*64
  int j = (int)(e & 63);
  int h2 = (int)((e >> 6) & 31);
  int bl = (int)(e >> 11);
  int l = bl & 2047, b = bl >> 11;
  float x1 = qr_raw[(size_t)bl * 2048 + h2 * 64 + j];
  float x2 = qr_raw[(size_t)bl * 2048 + h2 * 64 + (j ^ 32)];
  float val = rope_val(x1, x2, j, l);
  q_all[((size_t)((b * 32 + h2) * 2048 + l)) * 192 + 128 + j] = f2bf(val);
}

// k_r: tmp (4096 x 64 fp32) -> k_all[..., 128+j] broadcast to all 16 heads
__global__ __launch_bounds__(256) void rope_k_kernel(const float* __restrict__ kr_raw,
                                                     unsigned short* __restrict__ k_all) {
  size_t e = (size_t)blockIdx.x * 256 + threadIdx.x;  // 4096*64
  int j = (int)(e & 63);
  int bl = (int)(e >> 6);
  int l = bl & 2047, b = bl >> 11;
  float x1 = kr_raw[(size_t)bl * 64 + j];
  float x2 = kr_raw[(size_t)bl * 64 + (j ^ 32)];
  unsigned short hv = f2bf(rope_val(x1, x2, j, l));
#pragma unroll
  for (int h = 0; h < 16; h++)
    k_all[((size_t)((b * 16 + h) * 2048 + l)) * 192 + 128 + j] = hv;
}

// ---------------- lambda = sigmoid(x @ W_l + b_l), fp32 ----------------
__global__ __launch_bounds__(256) void lambda_kernel(const float* __restrict__ x,
                                                     const float* __restrict__ Wl,
                                                     const float* __restrict__ bl_,
                                                     float* __restrict__ lam) {
  int row = blockIdx.x, tid = threadIdx.x;
  int c = tid & 15, g = tid >> 4;
  const float* xr = x + (size_t)row * kDim;
  float acc = 0.f;
#pragma unroll 4
  for (int i = 0; i < 128; i++) {
    int k = g + i * 16;
    acc += xr[k] * Wl[(size_t)k * 16 + c];
  }
  __shared__ float red[256];
  red[tid] = acc;
  __syncthreads();
  if (tid < 16) {
    float t = 0.f;
#pragma unroll
    for (int j = 0; j < 16; j++) t += red[j * 16 + tid];
    float z = t + bl_[tid];
    lam[(size_t)row * 16 + tid] = 1.f / (1.f + __expf(-z));
  }
}

// ---------------- flash attention ----------------
// grid (qt=L/64, h2=2*NH, b). block 256 (4 waves, 16 Q-rows each).
// q_all [b,h2,l,192], k_all [b,n,l,192], v_allT [b,n,d,l], attn_o [b,h2,l,128]
__global__ __launch_bounds__(256) void attn_kernel(const unsigned short* __restrict__ q_all,
                                                   const unsigned short* __restrict__ k_all,
                                                   const unsigned short* __restrict__ v_allT,
                                                   unsigned short* __restrict__ attn_o) {
  __shared__ unsigned short lds_k[32 * 200];  // [pos][feat], stride 200 (2-way banks)
  __shared__ unsigned short lds_v[128 * 40];  // [d][pos], stride 40
  __shared__ unsigned short lds_p[4 * 640];   // per-wave P 16x32, stride 40
  int qt = blockIdx.x, h2 = blockIdx.y, b = blockIdx.z;
  int n = h2 >> 1;
  int tid = threadIdx.x, lane = tid & 63, w = tid >> 6, quad = lane >> 4, l16 = lane & 15;
  const unsigned short* q_head = q_all + ((size_t)(b * 32 + h2) * 2048) * 192;
  const unsigned short* k_head = k_all + ((size_t)(b * 16 + n) * 2048) * 192;
  const unsigned short* v_head = v_allT + ((size_t)(b * 16 + n) * 128) * 2048;
  unsigned short* o_head = attn_o + ((size_t)(b * 32 + h2) * 2048) * 128;

  int qrow = qt * 64 + w * 16;
  bf16x8 qf[6];
  const unsigned short* qr = q_head + (size_t)(qrow + l16) * 192;
#pragma unroll
  for (int ks = 0; ks < 6; ks++)
    qf[ks] = *reinterpret_cast<const bf16x8*>(&qr[ks * 32 + quad * 8]);

  f32x4 acc_o[8] = {};
  float m_i[4], l_i[4];
#pragma unroll
  for (int r = 0; r < 4; r++) { m_i[r] = -1e30f; l_i[r] = 0.f; }

  int nkt = qt * 2 + 2;
  for (int kt = 0; kt < nkt; kt++) {
    int pos0 = kt * 32;
    __syncthreads();
    // stage K tile (32 x 192)
#pragma unroll
    for (int c = 0; c < 3; c++) {
      int chunk = tid + c * 256;
      int row = chunk / 24, off = (chunk % 24) * 8;
      *reinterpret_cast<bf16x8*>(&lds_k[row * 200 + off]) =
          *reinterpret_cast<const bf16x8*>(&k_head[(size_t)(pos0 + row) * 192 + off]);
    }
    // stage V^T tile (128 x 32)
#pragma unroll
    for (int c = 0; c < 2; c++) {
      int chunk = tid + c * 256;
      int d = chunk >> 2, po = (chunk & 3) * 8;
      *reinterpret_cast<bf16x8*>(&lds_v[d * 40 + po]) =
          *reinterpret_cast<const bf16x8*>(&v_head[(size_t)d * 2048 + pos0 + po]);
    }
    __syncthreads();
    bool active = pos0 <= qrow + 15;
    if (active) {
      f32x4 s[2] = {};
#pragma unroll
      for (int ks = 0; ks < 6; ks++) {
        bf16x8 b0 = *reinterpret_cast<const bf16x8*>(&lds_k[l16 * 200 + ks * 32 + quad * 8]);
        bf16x8 b1 = *reinterpret_cast<const bf16x8*>(&lds_k[(16 + l16) * 200 + ks * 32 + quad * 8]);
        s[0] = mfma16(qf[ks], b0, s[0]);
        s[1] = mfma16(qf[ks], b1, s[1]);
      }
      float mt_[4];
#pragma unroll
      for (int r = 0; r < 4; r++) {
        int row = qrow + quad * 4 + r;
        float s0 = s[0][r] * kScale;
        float s1 = s[1][r] * kScale;
        if (pos0 + l16 > row) s0 = -1e30f;
        if (pos0 + 16 + l16 > row) s1 = -1e30f;
        s[0][r] = s0; s[1][r] = s1;
        float mx = fmaxf(s0, s1);
        mx = fmaxf(mx, __shfl_xor(mx, 1));
        mx = fmaxf(mx, __shfl_xor(mx, 2));
        mx = fmaxf(mx, __shfl_xor(mx, 4));
        mx = fmaxf(mx, __shfl_xor(mx, 8));
        mt_[r] = mx;
      }
      float alpha[4];
#pragma unroll
      for (int r = 0; r < 4; r++) {
        float mnew = fmaxf(m_i[r], mt_[r]);
        alpha[r] = __expf(m_i[r] - mnew);
        m_i[r] = mnew;
        float p0 = __expf(s[0][r] - mnew);
        float p1 = __expf(s[1][r] - mnew);
        float rs = p0 + p1;
        rs += __shfl_xor(rs, 1); rs += __shfl_xor(rs, 2);
        rs += __shfl_xor(rs, 4); rs += __shfl_xor(rs, 8);
        l_i[r] = l_i[r] * alpha[r] + rs;
        lds_p[w * 640 + (quad * 4 + r) * 40 + l16] = f2bf(p0);
        lds_p[w * 640 + (quad * 4 + r) * 40 + 16 + l16] = f2bf(p1);
      }
#pragma unroll
      for (int dt = 0; dt < 8; dt++)
#pragma unroll
        for (int r = 0; r < 4; r++) acc_o[dt][r] *= alpha[r];
    }
    __syncthreads();  // lds_p write->read ordering (uniform barrier count)
    if (active) {
      bf16x8 pf = *reinterpret_cast<const bf16x8*>(&lds_p[w * 640 + l16 * 40 + quad * 8]);
#pragma unroll
      for (int dt = 0; dt < 8; dt++) {
        bf16x8 vf = *reinterpret_cast<const bf16x8*>(&lds_v[(dt * 16 + l16) * 40 + quad * 8]);
        acc_o[dt] = mfma16(pf, vf, acc_o[dt]);
      }
    }
  }
#pragma unroll
  for (int r = 0; r < 4; r++) {
    float inv = 1.0f / l_i[r];
    int row = qrow + quad * 4 + r;
#pragma unroll
    for (int dt = 0; dt < 8; dt++)
      o_head[(size_t)row * 128 + dt * 16 + l16] = f2bf(acc_o[dt][r] * inv);
  }
}

// ---------------- combine: attn1 - lam*attn2 -> bf16 [bl][n*128+d] ----------------
__global__ __launch_bounds__(256) void combine_kernel(const unsigned short* __restrict__ attn_o,
                                                      const float* __restrict__ lam,
                                                      unsigned short* __restrict__ out) {
  size_t e = (size_t)blockIdx.x * 256 + threadIdx.x;  // 4096*2048
  int c = (int)(e & 2047);
  int bl = (int)(e >> 11);
  int n = c >> 7, d = c & 127;
  int b = bl >> 11, l = bl & 2047;
  size_t base = ((size_t)((b * 32 + n * 2) * 2048 + l)) * 128 + d;
  float a1 = bf2f(attn_o[base]);
  float a2 = bf2f(attn_o[base + (size_t)2048 * 128]);
  float lm = lam[(size_t)bl * 16 + n];
  out[e] = f2bf(a1 - lm * a2);
}

void launch_gemm(int mode, const unsigned short* A, const unsigned short* Bt, void* dst,
                 int M, int N, int K, hipStream_t s) {
  dim3 g(N / 64, M / 64), blk(256);
  switch (mode) {
    case 0: hipLaunchKernelGGL(gemm_bt_kernel<0>, g, blk, 0, s, A, Bt, dst, M, N, K); break;
    case 1: hipLaunchKernelGGL(gemm_bt_kernel<1>, g, blk, 0, s, A, Bt, dst, M, N, K); break;
    case 2: hipLaunchKernelGGL(gemm_bt_kernel<2>, g, blk, 0, s, A, Bt, dst, M, N, K); break;
    case 3: hipLaunchKernelGGL(gemm_bt_kernel<3>, g, blk, 0, s, A, Bt, dst, M, N, K); break;
  }
}

}  // namespace

extern "C" void kernel_launch(void* const* d_in, const int* in_sizes, int n_in,
                              void* d_out, int out_size, void* d_ws, size_t ws_size,
                              hipStream_t stream) {
  const float* x      = (const float*)d_in[0];
  const float* W_DKV  = (const float*)d_in[1];
  const float* kvnw   = (const float*)d_in[2];
  const float* W_UK   = (const float*)d_in[3];
  const float* W_UV   = (const float*)d_in[4];
  const float* W_DQ   = (const float*)d_in[5];
  const float* qnw    = (const float*)d_in[6];
  const float* W_UQ   = (const float*)d_in[7];
  const float* W_QR   = (const float*)d_in[8];
  const float* W_KR   = (const float*)d_in[9];
  const float* W_lw   = (const float*)d_in[10];
  const float* W_lb   = (const float*)d_in[11];
  const float* W_out  = (const float*)d_in[12];
  float* out = (float*)d_out;

  // ---- workspace carve (bytes), total ~254 MB ----
  char* ws = (char*)d_ws;
  size_t off = 0;
  auto alloc = [&](size_t bytes) { char* p = ws + off; off += (bytes + 255) & ~(size_t)255; return p; };
  unsigned short* xb     = (unsigned short*)alloc((size_t)4096 * 2048 * 2);
  unsigned short* wdkv   = (unsigned short*)alloc((size_t)1024 * 2048 * 2);
  unsigned short* wdq    = (unsigned short*)alloc((size_t)1024 * 2048 * 2);
  unsigned short* wuk    = (unsigned short*)alloc((size_t)2048 * 1024 * 2);
  unsigned short* wuv    = (unsigned short*)alloc((size_t)2048 * 1024 * 2);
  unsigned short* wuq    = (unsigned short*)alloc((size_t)4096 * 1024 * 2);
  unsigned short* wqr    = (unsigned short*)alloc((size_t)2048 * 1024 * 2);
  unsigned short* wkr    = (unsigned short*)alloc((size_t)64 * 2048 * 2);
  unsigned short* wout   = (unsigned short*)alloc((size_t)2048 * 2048 * 2);
  unsigned short* ckv    = (unsigned short*)alloc((size_t)4096 * 1024 * 2);
  unsigned short* cq     = (unsigned short*)alloc((size_t)4096 * 1024 * 2);
  unsigned short* k_all  = (unsigned short*)alloc((size_t)2 * 16 * 2048 * 192 * 2);
  unsigned short* v_allT = (unsigned short*)alloc((size_t)2 * 16 * 128 * 2048 * 2);
  unsigned short* q_all  = (unsigned short*)alloc((size_t)2 * 32 * 2048 * 192 * 2);
  unsigned short* attn_o = (unsigned short*)alloc((size_t)2 * 32 * 2048 * 128 * 2);
  unsigned short* attn_b = (unsigned short*)alloc((size_t)4096 * 2048 * 2);
  float* lam             = (float*)alloc((size_t)4096 * 16 * 4);
  float* tmpA            = (float*)alloc((size_t)4096 * 1024 * 4);
  float* tmpB            = (float*)alloc((size_t)4096 * 2048 * 4);
  float* tmpC            = (float*)alloc((size_t)4096 * 64 * 4);
  (void)ws_size; (void)in_sizes; (void)n_in; (void)out_size;

  // ---- convert x and weights (weights transposed to NxK bf16) ----
  hipLaunchKernelGGL(conv_bf16_kernel, dim3(8192), dim3(256), 0, stream, x, xb, 2097152);
  hipLaunchKernelGGL(transpose_conv_kernel, dim3(32, 64), dim3(256), 0, stream, W_DKV, wdkv, 2048, 1024);
  hipLaunchKernelGGL(transpose_conv_kernel, dim3(32, 64), dim3(256), 0, stream, W_DQ, wdq, 2048, 1024);
  hipLaunchKernelGGL(transpose_conv_kernel, dim3(64, 32), dim3(256), 0, stream, W_UK, wuk, 1024, 2048);
  hipLaunchKernelGGL(transpose_conv_kernel, dim3(64, 32), dim3(256), 0, stream, W_UV, wuv, 1024, 2048);
  hipLaunchKernelGGL(transpose_conv_kernel, dim3(128, 32), dim3(256), 0, stream, W_UQ, wuq, 1024, 4096);
  hipLaunchKernelGGL(transpose_conv_kernel, dim3(64, 32), dim3(256), 0, stream, W_QR, wqr, 1024, 2048);
  hipLaunchKernelGGL(transpose_conv_kernel, dim3(2, 64), dim3(256), 0, stream, W_KR, wkr, 2048, 64);
  hipLaunchKernelGGL(transpose_conv_kernel, dim3(64, 64), dim3(256), 0, stream, W_out, wout, 2048, 2048);

  // ---- down-projections + RMS ----
  launch_gemm(0, xb, wdkv, tmpA, 4096, 1024, 2048, stream);
  hipLaunchKernelGGL(rms_kernel, dim3(4096), dim3(256), 0, stream, tmpA, kvnw, ckv);
  launch_gemm(0, xb, wdq, tmpA, 4096, 1024, 2048, stream);
  hipLaunchKernelGGL(rms_kernel, dim3(4096), dim3(256), 0, stream, tmpA, qnw, cq);

  // ---- up-projections with pack epilogues ----
  launch_gemm(1, ckv, wuk, k_all, 4096, 2048, 1024, stream);   // K_c
  launch_gemm(2, ckv, wuv, v_allT, 4096, 2048, 1024, stream);  // V (transposed)
  launch_gemm(3, cq, wuq, q_all, 4096, 4096, 1024, stream);    // Q_c
  launch_gemm(0, cq, wqr, tmpB, 4096, 2048, 1024, stream);     // Q_r raw
  launch_gemm(0, xb, wkr, tmpC, 4096, 64, 2048, stream);       // K_r raw

  // ---- rope packs + lambda ----
  hipLaunchKernelGGL(rope_q_kernel, dim3(32768), dim3(256), 0, stream, tmpB, q_all);
  hipLaunchKernelGGL(rope_k_kernel, dim3(1024), dim3(256), 0, stream, tmpC, k_all);
  hipLaunchKernelGGL(lambda_kernel, dim3(4096), dim3(256), 0, stream, x, W_lw, W_lb, lam);

  // ---- attention ----
  hipLaunchKernelGGL(attn_kernel, dim3(32, 32, 2), dim3(256), 0, stream, q_all, k_all, v_allT, attn_o);

  // ---- combine + output projection ----
  hipLaunchKernelGGL(combine_kernel, dim3(32768), dim3(256), 0, stream, attn_o, lam, attn_b);
  launch_gemm(0, attn_b, wout, out, 4096, 2048, 2048, stream);
}

// Round 2
// 1072.161 us; speedup vs baseline: 1.0485x; 1.0485x over previous
//
#include <hip/hip_runtime.h>
#include <cstddef>
#include <cstdint>

// DiffMLA attention, MI355X.
// R2: GEMMs upgraded to m97 structure (128x128 tile, global_load_lds width=16,
// BK=32, 4 waves x 4x4 MFMA accs). Attention unchanged (round 3 target).

namespace {

constexpr int kBatch = 2, kLen = 2048, kDim = 2048, kNH = 16, kDH = 128, kDHR = 64, kDC = 1024;
constexpr float kScale = 0.07216878364870323f;  // 1/sqrt(192)

typedef __bf16 bf16x8 __attribute__((ext_vector_type(8)));
typedef float f32x4 __attribute__((ext_vector_type(4)));

__device__ __forceinline__ unsigned short f2bf(float f) {
  union { float f; unsigned int u; } v; v.f = f;
  unsigned int r = v.u + 0x7FFFu + ((v.u >> 16) & 1u);
  return (unsigned short)(r >> 16);
}
__device__ __forceinline__ float bf2f(unsigned short h) {
  union { unsigned int u; float f; } v; v.u = ((unsigned int)h) << 16;
  return v.f;
}
__device__ __forceinline__ f32x4 mfma16(bf16x8 a, bf16x8 b, f32x4 c) {
  return __builtin_amdgcn_mfma_f32_16x16x32_bf16(a, b, c, 0, 0, 0);
}
// async global->LDS, 16B per lane; lds base must be wave-uniform (lane scatters +lane*16)
__device__ __forceinline__ void gl_lds16(const void* g, void* l) {
  __builtin_amdgcn_global_load_lds(
      (const __attribute__((address_space(1))) unsigned int*)g,
      (__attribute__((address_space(3))) unsigned int*)l, 16, 0, 0);
}

// ---------------- elementwise convert f32 -> bf16 (x4 vectorized) ----------------
__global__ __launch_bounds__(256) void conv_bf16_kernel(const float* __restrict__ in,
                                                        unsigned short* __restrict__ out, int n4) {
  int e = blockIdx.x * 256 + threadIdx.x;
  if (e >= n4) return;
  float4 v = reinterpret_cast<const float4*>(in)[e];
  uint2 pk;
  pk.x = (unsigned int)f2bf(v.x) | ((unsigned int)f2bf(v.y) << 16);
  pk.y = (unsigned int)f2bf(v.z) | ((unsigned int)f2bf(v.w) << 16);
  reinterpret_cast<uint2*>(out)[e] = pk;
}

// ------------- transpose+convert: in (K x N) f32 -> out (N x K) bf16 -------------
__global__ __launch_bounds__(256) void transpose_conv_kernel(const float* __restrict__ in,
                                                             unsigned short* __restrict__ out,
                                                             int K, int N) {
  __shared__ float t[32][33];
  int n0 = blockIdx.x * 32, k0 = blockIdx.y * 32;
  int tx = threadIdx.x & 31, ty = threadIdx.x >> 5;
#pragma unroll
  for (int i = 0; i < 4; i++) t[ty + i * 8][tx] = in[(size_t)(k0 + ty + i * 8) * N + n0 + tx];
  __syncthreads();
#pragma unroll
  for (int i = 0; i < 4; i++)
    out[(size_t)(n0 + ty + i * 8) * K + k0 + tx] = f2bf(t[tx][ty + i * 8]);
}

// ---------------- epilogue scatter (shared by both GEMM kernels) ----------------
// MODE 0: dst = fp32 row-major C
// MODE 1: dst = k_all bf16, col=(h*128+d) -> [((b*16+h)*2048+l)*192 + d]
// MODE 2: dst = v_allT bf16, col=(h*128+d) -> [((b*16+h)*128+d)*2048 + l]
// MODE 3: dst = q_all bf16, col=(h2*128+d) -> [((b*32+h2)*2048+l)*192 + d]
template <int MODE>
__device__ __forceinline__ void epi_store(void* dst, int gr, int gc, int N, float v) {
  if (MODE == 0) {
    reinterpret_cast<float*>(dst)[(size_t)gr * N + gc] = v;
  } else {
    int bb = gr >> 11, l = gr & 2047;
    unsigned short hv = f2bf(v);
    unsigned short* o = reinterpret_cast<unsigned short*>(dst);
    if (MODE == 1) {
      int h = gc >> 7, d2 = gc & 127;
      o[((size_t)((bb * 16 + h) * 2048 + l)) * 192 + d2] = hv;
    } else if (MODE == 2) {
      int h = gc >> 7, d2 = gc & 127;
      o[((size_t)((bb * 16 + h) * 128 + d2)) * 2048 + l] = hv;
    } else {
      int h2 = gc >> 7, d2 = gc & 127;
      o[((size_t)((bb * 32 + h2) * 2048 + l)) * 192 + d2] = hv;
    }
  }
}

// ---- m97-structure GEMM: C(MxN) = A(MxK) * Bt(NxK)^T, 128x128 tile, BK=32 ----
// LDS layout unpadded [row][k0..31] (stride 32 elems = 64B), contiguous in the
// exact lane order global_load_lds scatters (wave-uniform base + lane*16B).
template <int MODE>
__global__ __launch_bounds__(256) void gemm128_kernel(const unsigned short* __restrict__ A,
                                                      const unsigned short* __restrict__ Bt,
                                                      void* __restrict__ dst, int M, int N, int K) {
  __shared__ unsigned short lds_a[128 * 32];
  __shared__ unsigned short lds_b[128 * 32];
  int tid = threadIdx.x, lane = tid & 63, w = tid >> 6;
  int quad = lane >> 4, l16 = lane & 15;
  int wr = w >> 1, wc = w & 1;
  int mbase = blockIdx.y * 128, nbase = blockIdx.x * 128;
  f32x4 acc[4][4] = {};
  // staging: chunk c = r*256 + tid covers row c>>2, koff (c&3)*8; LDS byte off = c*16
  int srow0 = tid >> 2, skoff = (tid & 3) * 8;
  const size_t a_base = (size_t)(mbase + srow0) * K + skoff;
  const size_t b_base = (size_t)(nbase + srow0) * K + skoff;
  unsigned short* lba0 = &lds_a[(size_t)(w * 64) * 8];
  unsigned short* lba1 = &lds_a[(size_t)(256 + w * 64) * 8];
  unsigned short* lbb0 = &lds_b[(size_t)(w * 64) * 8];
  unsigned short* lbb1 = &lds_b[(size_t)(256 + w * 64) * 8];
  for (int k0 = 0; k0 < K; k0 += 32) {
    __syncthreads();
    gl_lds16(&A[a_base + k0], lba0);
    gl_lds16(&A[a_base + (size_t)64 * K + k0], lba1);
    gl_lds16(&Bt[b_base + k0], lbb0);
    gl_lds16(&Bt[b_base + (size_t)64 * K + k0], lbb1);
    __syncthreads();
    bf16x8 af[4], bfr[4];
#pragma unroll
    for (int i = 0; i < 4; i++) {
      af[i] = *reinterpret_cast<const bf16x8*>(&lds_a[(wr * 64 + i * 16 + l16) * 32 + quad * 8]);
      bfr[i] = *reinterpret_cast<const bf16x8*>(&lds_b[(wc * 64 + i * 16 + l16) * 32 + quad * 8]);
    }
#pragma unroll
    for (int i = 0; i < 4; i++)
#pragma unroll
      for (int j = 0; j < 4; j++) acc[i][j] = mfma16(af[i], bfr[j], acc[i][j]);
  }
#pragma unroll
  for (int i = 0; i < 4; i++)
#pragma unroll
    for (int j = 0; j < 4; j++)
#pragma unroll
      for (int r = 0; r < 4; r++) {
        int gr = mbase + wr * 64 + i * 16 + quad * 4 + r;
        int gc = nbase + wc * 64 + j * 16 + l16;
        epi_store<MODE>(dst, gr, gc, N, acc[i][j][r]);
      }
}

// ---- fallback 64x64 GEMM (for N=64 W_KR projection) ----
template <int MODE>
__global__ __launch_bounds__(256) void gemm_bt_kernel(const unsigned short* __restrict__ A,
                                                      const unsigned short* __restrict__ Bt,
                                                      void* __restrict__ dst, int M, int N, int K) {
  __shared__ unsigned short lds_a[64 * 40];
  __shared__ unsigned short lds_b[64 * 40];
  int tid = threadIdx.x;
  int lane = tid & 63, w = tid >> 6;
  int quad = lane >> 4, l16 = lane & 15;
  int wr = w >> 1, wc = w & 1;
  int nbase = blockIdx.x * 64, mbase = blockIdx.y * 64;
  f32x4 acc[2][2] = {};
  int srow = tid >> 2;
  int skoff = (tid & 3) * 8;
  const size_t a_off = (size_t)(mbase + srow) * K + skoff;
  const size_t b_off = (size_t)(nbase + srow) * K + skoff;
  for (int k0 = 0; k0 < K; k0 += 32) {
    __syncthreads();
    *reinterpret_cast<bf16x8*>(&lds_a[srow * 40 + skoff]) =
        *reinterpret_cast<const bf16x8*>(&A[a_off + k0]);
    *reinterpret_cast<bf16x8*>(&lds_b[srow * 40 + skoff]) =
        *reinterpret_cast<const bf16x8*>(&Bt[b_off + k0]);
    __syncthreads();
    bf16x8 af0 = *reinterpret_cast<const bf16x8*>(&lds_a[(wr * 32 + l16) * 40 + quad * 8]);
    bf16x8 af1 = *reinterpret_cast<const bf16x8*>(&lds_a[(wr * 32 + 16 + l16) * 40 + quad * 8]);
    bf16x8 bf0 = *reinterpret_cast<const bf16x8*>(&lds_b[(wc * 32 + l16) * 40 + quad * 8]);
    bf16x8 bf1 = *reinterpret_cast<const bf16x8*>(&lds_b[(wc * 32 + 16 + l16) * 40 + quad * 8]);
    acc[0][0] = mfma16(af0, bf0, acc[0][0]);
    acc[0][1] = mfma16(af0, bf1, acc[0][1]);
    acc[1][0] = mfma16(af1, bf0, acc[1][0]);
    acc[1][1] = mfma16(af1, bf1, acc[1][1]);
  }
#pragma unroll
  for (int mt = 0; mt < 2; mt++)
#pragma unroll
    for (int nt = 0; nt < 2; nt++)
#pragma unroll
      for (int r = 0; r < 4; r++) {
        int gr = mbase + wr * 32 + mt * 16 + quad * 4 + r;
        int gc = nbase + wc * 32 + nt * 16 + l16;
        epi_store<MODE>(dst, gr, gc, N, acc[mt][nt][r]);
      }
}

// ---------------- RMS norm: in fp32 (rows x 1024) -> out bf16 ----------------
__global__ __launch_bounds__(256) void rms_kernel(const float* __restrict__ in,
                                                  const float* __restrict__ w,
                                                  unsigned short* __restrict__ out) {
  int row = blockIdx.x, tid = threadIdx.x;
  float4 v = reinterpret_cast<const float4*>(in + (size_t)row * kDC)[tid];
  float ss = v.x * v.x + v.y * v.y + v.z * v.z + v.w * v.w;
  ss += __shfl_xor(ss, 1); ss += __shfl_xor(ss, 2); ss += __shfl_xor(ss, 4);
  ss += __shfl_xor(ss, 8); ss += __shfl_xor(ss, 16); ss += __shfl_xor(ss, 32);
  __shared__ float red[4];
  if ((tid & 63) == 0) red[tid >> 6] = ss;
  __syncthreads();
  float tot = red[0] + red[1] + red[2] + red[3];
  float rs = rsqrtf(tot * (1.0f / kDC) + 1e-6f);
  float4 wv = reinterpret_cast<const float4*>(w)[tid];
  uint2 pk;
  pk.x = (unsigned int)f2bf(v.x * rs * wv.x) | ((unsigned int)f2bf(v.y * rs * wv.y) << 16);
  pk.y = (unsigned int)f2bf(v.z * rs * wv.z) | ((unsigned int)f2bf(v.w * rs * wv.w) << 16);
  reinterpret_cast<uint2*>(out)[(size_t)row * 256 + tid] = pk;
}

// ---------------- RoPE helpers ----------------
__device__ __forceinline__ float rope_val(float x1, float x2, int j, int l) {
  int i = j & 31;
  float inv_freq = powf(10000.0f, -(float)i * (1.0f / 32.0f));
  float ang = (float)l * inv_freq;
  float cv = cosf(ang), sv = sinf(ang);
  float rot = (j < 32) ? -x2 : x2;
  return x1 * cv + rot * sv;
}

__global__ __launch_bounds__(256) void rope_q_kernel(const float* __restrict__ qr_raw,
                                                     unsigned short* __restrict__ q_all) {
  size_t e = (size_t)blockIdx.x * 256 + threadIdx.x;  // 4096*32*64
  int j = (int)(e & 63);
  int h2 = (int)((e >> 6) & 31);
  int bl = (int)(e >> 11);
  int l = bl & 2047, b = bl >> 11;
  float x1 = qr_raw[(size_t)bl * 2048 + h2 * 64 + j];
  float x2 = qr_raw[(size_t)bl * 2048 + h2 * 64 + (j ^ 32)];
  float val = rope_val(x1, x2, j, l);
  q_all[((size_t)((b * 32 + h2) * 2048 + l)) * 192 + 128 + j] = f2bf(val);
}

__global__ __launch_bounds__(256) void rope_k_kernel(const float* __restrict__ kr_raw,
                                                     unsigned short* __restrict__ k_all) {
  size_t e = (size_t)blockIdx.x * 256 + threadIdx.x;  // 4096*64
  int j = (int)(e & 63);
  int bl = (int)(e >> 6);
  int l = bl & 2047, b = bl >> 11;
  float x1 = kr_raw[(size_t)bl * 64 + j];
  float x2 = kr_raw[(size_t)bl * 64 + (j ^ 32)];
  unsigned short hv = f2bf(rope_val(x1, x2, j, l));
#pragma unroll
  for (int h = 0; h < 16; h++)
    k_all[((size_t)((b * 16 + h) * 2048 + l)) * 192 + 128 + j] = hv;
}

// ---------------- lambda = sigmoid(x @ W_l + b_l), fp32 ----------------
__global__ __launch_bounds__(256) void lambda_kernel(const float* __restrict__ x,
                                                     const float* __restrict__ Wl,
                                                     const float* __restrict__ bl_,
                                                     float* __restrict__ lam) {
  int row = blockIdx.x, tid = threadIdx.x;
  int c = tid & 15, g = tid >> 4;
  const float* xr = x + (size_t)row * kDim;
  float acc = 0.f;
#pragma unroll 4
  for (int i = 0; i < 128; i++) {
    int k = g + i * 16;
    acc += xr[k] * Wl[(size_t)k * 16 + c];
  }
  __shared__ float red[256];
  red[tid] = acc;
  __syncthreads();
  if (tid < 16) {
    float t = 0.f;
#pragma unroll
    for (int j = 0; j < 16; j++) t += red[j * 16 + tid];
    float z = t + bl_[tid];
    lam[(size_t)row * 16 + tid] = 1.f / (1.f + __expf(-z));
  }
}

// ---------------- flash attention (unchanged this round) ----------------
__global__ __launch_bounds__(256) void attn_kernel(const unsigned short* __restrict__ q_all,
                                                   const unsigned short* __restrict__ k_all,
                                                   const unsigned short* __restrict__ v_allT,
                                                   unsigned short* __restrict__ attn_o) {
  __shared__ unsigned short lds_k[32 * 200];
  __shared__ unsigned short lds_v[128 * 40];
  __shared__ unsigned short lds_p[4 * 640];
  int qt = blockIdx.x, h2 = blockIdx.y, b = blockIdx.z;
  int n = h2 >> 1;
  int tid = threadIdx.x, lane = tid & 63, w = tid >> 6, quad = lane >> 4, l16 = lane & 15;
  const unsigned short* q_head = q_all + ((size_t)(b * 32 + h2) * 2048) * 192;
  const unsigned short* k_head = k_all + ((size_t)(b * 16 + n) * 2048) * 192;
  const unsigned short* v_head = v_allT + ((size_t)(b * 16 + n) * 128) * 2048;
  unsigned short* o_head = attn_o + ((size_t)(b * 32 + h2) * 2048) * 128;

  int qrow = qt * 64 + w * 16;
  bf16x8 qf[6];
  const unsigned short* qr = q_head + (size_t)(qrow + l16) * 192;
#pragma unroll
  for (int ks = 0; ks < 6; ks++)
    qf[ks] = *reinterpret_cast<const bf16x8*>(&qr[ks * 32 + quad * 8]);

  f32x4 acc_o[8] = {};
  float m_i[4], l_i[4];
#pragma unroll
  for (int r = 0; r < 4; r++) { m_i[r] = -1e30f; l_i[r] = 0.f; }

  int nkt = qt * 2 + 2;
  for (int kt = 0; kt < nkt; kt++) {
    int pos0 = kt * 32;
    __syncthreads();
#pragma unroll
    for (int c = 0; c < 3; c++) {
      int chunk = tid + c * 256;
      int row = chunk / 24, off = (chunk % 24) * 8;
      *reinterpret_cast<bf16x8*>(&lds_k[row * 200 + off]) =
          *reinterpret_cast<const bf16x8*>(&k_head[(size_t)(pos0 + row) * 192 + off]);
    }
#pragma unroll
    for (int c = 0; c < 2; c++) {
      int chunk = tid + c * 256;
      int d = chunk >> 2, po = (chunk & 3) * 8;
      *reinterpret_cast<bf16x8*>(&lds_v[d * 40 + po]) =
          *reinterpret_cast<const bf16x8*>(&v_head[(size_t)d * 2048 + pos0 + po]);
    }
    __syncthreads();
    bool active = pos0 <= qrow + 15;
    if (active) {
      f32x4 s[2] = {};
#pragma unroll
      for (int ks = 0; ks < 6; ks++) {
        bf16x8 b0 = *reinterpret_cast<const bf16x8*>(&lds_k[l16 * 200 + ks * 32 + quad * 8]);
        bf16x8 b1 = *reinterpret_cast<const bf16x8*>(&lds_k[(16 + l16) * 200 + ks * 32 + quad * 8]);
        s[0] = mfma16(qf[ks], b0, s[0]);
        s[1] = mfma16(qf[ks], b1, s[1]);
      }
      float mt_[4];
#pragma unroll
      for (int r = 0; r < 4; r++) {
        int row = qrow + quad * 4 + r;
        float s0 = s[0][r] * kScale;
        float s1 = s[1][r] * kScale;
        if (pos0 + l16 > row) s0 = -1e30f;
        if (pos0 + 16 + l16 > row) s1 = -1e30f;
        s[0][r] = s0; s[1][r] = s1;
        float mx = fmaxf(s0, s1);
        mx = fmaxf(mx, __shfl_xor(mx, 1));
        mx = fmaxf(mx, __shfl_xor(mx, 2));
        mx = fmaxf(mx, __shfl_xor(mx, 4));
        mx = fmaxf(mx, __shfl_xor(mx, 8));
        mt_[r] = mx;
      }
      float alpha[4];
#pragma unroll
      for (int r = 0; r < 4; r++) {
        float mnew = fmaxf(m_i[r], mt_[r]);
        alpha[r] = __expf(m_i[r] - mnew);
        m_i[r] = mnew;
        float p0 = __expf(s[0][r] - mnew);
        float p1 = __expf(s[1][r] - mnew);
        float rs = p0 + p1;
        rs += __shfl_xor(rs, 1); rs += __shfl_xor(rs, 2);
        rs += __shfl_xor(rs, 4); rs += __shfl_xor(rs, 8);
        l_i[r] = l_i[r] * alpha[r] + rs;
        lds_p[w * 640 + (quad * 4 + r) * 40 + l16] = f2bf(p0);
        lds_p[w * 640 + (quad * 4 + r) * 40 + 16 + l16] = f2bf(p1);
      }
#pragma unroll
      for (int dt = 0; dt < 8; dt++)
#pragma unroll
        for (int r = 0; r < 4; r++) acc_o[dt][r] *= alpha[r];
    }
    __syncthreads();
    if (active) {
      bf16x8 pf = *reinterpret_cast<const bf16x8*>(&lds_p[w * 640 + l16 * 40 + quad * 8]);
#pragma unroll
      for (int dt = 0; dt < 8; dt++) {
        bf16x8 vf = *reinterpret_cast<const bf16x8*>(&lds_v[(dt * 16 + l16) * 40 + quad * 8]);
        acc_o[dt] = mfma16(pf, vf, acc_o[dt]);
      }
    }
  }
#pragma unroll
  for (int r = 0; r < 4; r++) {
    float inv = 1.0f / l_i[r];
    int row = qrow + quad * 4 + r;
#pragma unroll
    for (int dt = 0; dt < 8; dt++)
      o_head[(size_t)row * 128 + dt * 16 + l16] = f2bf(acc_o[dt][r] * inv);
  }
}

// ---------------- combine: attn1 - lam*attn2 -> bf16 [bl][n*128+d] ----------------
__global__ __launch_bounds__(256) void combine_kernel(const unsigned short* __restrict__ attn_o,
                                                      const float* __restrict__ lam,
                                                      unsigned short* __restrict__ out) {
  size_t e = (size_t)blockIdx.x * 256 + threadIdx.x;  // 4096*2048
  int c = (int)(e & 2047);
  int bl = (int)(e >> 11);
  int n = c >> 7, d = c & 127;
  int b = bl >> 11, l = bl & 2047;
  size_t base = ((size_t)((b * 32 + n * 2) * 2048 + l)) * 128 + d;
  float a1 = bf2f(attn_o[base]);
  float a2 = bf2f(attn_o[base + (size_t)2048 * 128]);
  float lm = lam[(size_t)bl * 16 + n];
  out[e] = f2bf(a1 - lm * a2);
}

void launch_gemm128(int mode, const unsigned short* A, const unsigned short* Bt, void* dst,
                    int M, int N, int K, hipStream_t s) {
  dim3 g(N / 128, M / 128), blk(256);
  switch (mode) {
    case 0: hipLaunchKernelGGL(gemm128_kernel<0>, g, blk, 0, s, A, Bt, dst, M, N, K); break;
    case 1: hipLaunchKernelGGL(gemm128_kernel<1>, g, blk, 0, s, A, Bt, dst, M, N, K); break;
    case 2: hipLaunchKernelGGL(gemm128_kernel<2>, g, blk, 0, s, A, Bt, dst, M, N, K); break;
    case 3: hipLaunchKernelGGL(gemm128_kernel<3>, g, blk, 0, s, A, Bt, dst, M, N, K); break;
  }
}

}  // namespace

extern "C" void kernel_launch(void* const* d_in, const int* in_sizes, int n_in,
                              void* d_out, int out_size, void* d_ws, size_t ws_size,
                              hipStream_t stream) {
  const float* x      = (const float*)d_in[0];
  const float* W_DKV  = (const float*)d_in[1];
  const float* kvnw   = (const float*)d_in[2];
  const float* W_UK   = (const float*)d_in[3];
  const float* W_UV   = (const float*)d_in[4];
  const float* W_DQ   = (const float*)d_in[5];
  const float* qnw    = (const float*)d_in[6];
  const float* W_UQ   = (const float*)d_in[7];
  const float* W_QR   = (const float*)d_in[8];
  const float* W_KR   = (const float*)d_in[9];
  const float* W_lw   = (const float*)d_in[10];
  const float* W_lb   = (const float*)d_in[11];
  const float* W_out  = (const float*)d_in[12];
  float* out = (float*)d_out;

  // ---- workspace carve (bytes) ----
  char* ws = (char*)d_ws;
  size_t off = 0;
  auto alloc = [&](size_t bytes) { char* p = ws + off; off += (bytes + 255) & ~(size_t)255; return p; };
  unsigned short* xb     = (unsigned short*)alloc((size_t)4096 * 2048 * 2);
  unsigned short* wdkv   = (unsigned short*)alloc((size_t)1024 * 2048 * 2);
  unsigned short* wdq    = (unsigned short*)alloc((size_t)1024 * 2048 * 2);
  unsigned short* wuk    = (unsigned short*)alloc((size_t)2048 * 1024 * 2);
  unsigned short* wuv    = (unsigned short*)alloc((size_t)2048 * 1024 * 2);
  unsigned short* wuq    = (unsigned short*)alloc((size_t)4096 * 1024 * 2);
  unsigned short* wqr    = (unsigned short*)alloc((size_t)2048 * 1024 * 2);
  unsigned short* wkr    = (unsigned short*)alloc((size_t)64 * 2048 * 2);
  unsigned short* wout   = (unsigned short*)alloc((size_t)2048 * 2048 * 2);
  unsigned short* ckv    = (unsigned short*)alloc((size_t)4096 * 1024 * 2);
  unsigned short* cq     = (unsigned short*)alloc((size_t)4096 * 1024 * 2);
  unsigned short* k_all  = (unsigned short*)alloc((size_t)2 * 16 * 2048 * 192 * 2);
  unsigned short* v_allT = (unsigned short*)alloc((size_t)2 * 16 * 128 * 2048 * 2);
  unsigned short* q_all  = (unsigned short*)alloc((size_t)2 * 32 * 2048 * 192 * 2);
  unsigned short* attn_o = (unsigned short*)alloc((size_t)2 * 32 * 2048 * 128 * 2);
  unsigned short* attn_b = (unsigned short*)alloc((size_t)4096 * 2048 * 2);
  float* lam             = (float*)alloc((size_t)4096 * 16 * 4);
  float* tmpA            = (float*)alloc((size_t)4096 * 1024 * 4);
  float* tmpB            = (float*)alloc((size_t)4096 * 2048 * 4);
  float* tmpC            = (float*)alloc((size_t)4096 * 64 * 4);
  (void)ws_size; (void)in_sizes; (void)n_in; (void)out_size;

  // ---- convert x and weights (weights transposed to NxK bf16) ----
  hipLaunchKernelGGL(conv_bf16_kernel, dim3(8192), dim3(256), 0, stream, x, xb, 2097152);
  hipLaunchKernelGGL(transpose_conv_kernel, dim3(32, 64), dim3(256), 0, stream, W_DKV, wdkv, 2048, 1024);
  hipLaunchKernelGGL(transpose_conv_kernel, dim3(32, 64), dim3(256), 0, stream, W_DQ, wdq, 2048, 1024);
  hipLaunchKernelGGL(transpose_conv_kernel, dim3(64, 32), dim3(256), 0, stream, W_UK, wuk, 1024, 2048);
  hipLaunchKernelGGL(transpose_conv_kernel, dim3(64, 32), dim3(256), 0, stream, W_UV, wuv, 1024, 2048);
  hipLaunchKernelGGL(transpose_conv_kernel, dim3(128, 32), dim3(256), 0, stream, W_UQ, wuq, 1024, 4096);
  hipLaunchKernelGGL(transpose_conv_kernel, dim3(64, 32), dim3(256), 0, stream, W_QR, wqr, 1024, 2048);
  hipLaunchKernelGGL(transpose_conv_kernel, dim3(2, 64), dim3(256), 0, stream, W_KR, wkr, 2048, 64);
  hipLaunchKernelGGL(transpose_conv_kernel, dim3(64, 64), dim3(256), 0, stream, W_out, wout, 2048, 2048);

  // ---- down-projections + RMS ----
  launch_gemm128(0, xb, wdkv, tmpA, 4096, 1024, 2048, stream);
  hipLaunchKernelGGL(rms_kernel, dim3(4096), dim3(256), 0, stream, tmpA, kvnw, ckv);
  launch_gemm128(0, xb, wdq, tmpA, 4096, 1024, 2048, stream);
  hipLaunchKernelGGL(rms_kernel, dim3(4096), dim3(256), 0, stream, tmpA, qnw, cq);

  // ---- up-projections with pack epilogues ----
  launch_gemm128(1, ckv, wuk, k_all, 4096, 2048, 1024, stream);   // K_c
  launch_gemm128(2, ckv, wuv, v_allT, 4096, 2048, 1024, stream);  // V (transposed)
  launch_gemm128(3, cq, wuq, q_all, 4096, 4096, 1024, stream);    // Q_c
  launch_gemm128(0, cq, wqr, tmpB, 4096, 2048, 1024, stream);     // Q_r raw
  hipLaunchKernelGGL(gemm_bt_kernel<0>, dim3(1, 64), dim3(256), 0, stream,
                     xb, wkr, tmpC, 4096, 64, 2048);              // K_r raw (N=64)

  // ---- rope packs + lambda ----
  hipLaunchKernelGGL(rope_q_kernel, dim3(32768), dim3(256), 0, stream, tmpB, q_all);
  hipLaunchKernelGGL(rope_k_kernel, dim3(1024), dim3(256), 0, stream, tmpC, k_all);
  hipLaunchKernelGGL(lambda_kernel, dim3(4096), dim3(256), 0, stream, x, W_lw, W_lb, lam);

  // ---- attention ----
  hipLaunchKernelGGL(attn_kernel, dim3(32, 32, 2), dim3(256), 0, stream, q_all, k_all, v_allT, attn_o);

  // ---- combine + output projection ----
  hipLaunchKernelGGL(combine_kernel, dim3(32768), dim3(256), 0, stream, attn_o, lam, attn_b);
  launch_gemm128(0, attn_b, wout, out, 4096, 2048, 2048, stream);
}

// Round 4
// 879.066 us; speedup vs baseline: 1.2788x; 1.2197x over previous
//
#include <hip/hip_runtime.h>
#include <cstddef>
#include <cstdint>

// DiffMLA attention, MI355X.
// R4 = R3 + correctness hardening:
//  - attn2: restored __syncthreads() between P LDS write and P LDS read
//    (same-wave ds_write->ds_read ordering is NOT guaranteed without a wait;
//    R3's replay-only divergence matched this failure mode).
//  - wd_cat pad rows [2112,2176) explicitly zeroed (was uninit-read, dropped).

namespace {

constexpr int kDC = 1024, kDim = 2048;
constexpr float kScale = 0.07216878364870323f;  // 1/sqrt(192)

typedef __bf16 bf16x8 __attribute__((ext_vector_type(8)));
typedef float f32x4 __attribute__((ext_vector_type(4)));

__device__ __forceinline__ unsigned short f2bf(float f) {
  union { float f; unsigned int u; } v; v.f = f;
  unsigned int r = v.u + 0x7FFFu + ((v.u >> 16) & 1u);
  return (unsigned short)(r >> 16);
}
__device__ __forceinline__ float bf2f(unsigned short h) {
  union { unsigned int u; float f; } v; v.u = ((unsigned int)h) << 16;
  return v.f;
}
__device__ __forceinline__ f32x4 mfma16(bf16x8 a, bf16x8 b, f32x4 c) {
  return __builtin_amdgcn_mfma_f32_16x16x32_bf16(a, b, c, 0, 0, 0);
}
__device__ __forceinline__ void gl_lds16(const void* g, void* l) {
  __builtin_amdgcn_global_load_lds(
      (const __attribute__((address_space(1))) unsigned int*)g,
      (__attribute__((address_space(3))) unsigned int*)l, 16, 0, 0);
}

// ---------------- convert f32 -> bf16 ----------------
__global__ __launch_bounds__(256) void conv_bf16_kernel(const float* __restrict__ in,
                                                        unsigned short* __restrict__ out, int n4) {
  int e = blockIdx.x * 256 + threadIdx.x;
  if (e >= n4) return;
  float4 v = reinterpret_cast<const float4*>(in)[e];
  uint2 pk;
  pk.x = (unsigned int)f2bf(v.x) | ((unsigned int)f2bf(v.y) << 16);
  pk.y = (unsigned int)f2bf(v.z) | ((unsigned int)f2bf(v.w) << 16);
  reinterpret_cast<uint2*>(out)[e] = pk;
}

// ---------------- zero-fill bf16 region ----------------
__global__ __launch_bounds__(256) void zero_bf16_kernel(unsigned short* __restrict__ out, int n8) {
  int e = blockIdx.x * 256 + threadIdx.x;
  if (e >= n8) return;
  reinterpret_cast<uint4*>(out)[e] = uint4{0, 0, 0, 0};
}

// ------------- transpose+convert: in (K x N) f32 -> out (N x K) bf16 -------------
__global__ __launch_bounds__(256) void transpose_conv_kernel(const float* __restrict__ in,
                                                             unsigned short* __restrict__ out,
                                                             int K, int N) {
  __shared__ float t[32][33];
  int n0 = blockIdx.x * 32, k0 = blockIdx.y * 32;
  int tx = threadIdx.x & 31, ty = threadIdx.x >> 5;
#pragma unroll
  for (int i = 0; i < 4; i++) t[ty + i * 8][tx] = in[(size_t)(k0 + ty + i * 8) * N + n0 + tx];
  __syncthreads();
#pragma unroll
  for (int i = 0; i < 4; i++)
    out[(size_t)(n0 + ty + i * 8) * K + k0 + tx] = f2bf(t[tx][ty + i * 8]);
}

// ---------------- epilogue ----------------
// MODE 0: fp32 row-major C (stride N)
// MODE 4: fused down-proj: fp32 stride 2112; cols 0..1023 c_kv | 1024..2047 c_q
//         | 2048..2111 k_r | >=2112 dropped
// MODE 5: fused UK|UV: gc<2048 -> k_all pack; else v_allT pack
// MODE 6: fused UQ|QR: gc<4096 -> q_all pack (x kScale); else tmpB fp32 (stride 2048)
template <int MODE>
__device__ __forceinline__ void epi_store(void* dst, void* dst2, int gr, int gc, int N, float v) {
  if (MODE == 0) {
    reinterpret_cast<float*>(dst)[(size_t)gr * N + gc] = v;
  } else if (MODE == 4) {
    if (gc < 2112) reinterpret_cast<float*>(dst)[(size_t)gr * 2112 + gc] = v;
  } else if (MODE == 5) {
    int bb = gr >> 11, l = gr & 2047;
    unsigned short hv = f2bf(v);
    if (gc < 2048) {
      int h = gc >> 7, d2 = gc & 127;
      reinterpret_cast<unsigned short*>(dst)[((size_t)((bb * 16 + h) * 2048 + l)) * 192 + d2] = hv;
    } else {
      int g2 = gc - 2048, h = g2 >> 7, d2 = g2 & 127;
      reinterpret_cast<unsigned short*>(dst2)[((size_t)((bb * 16 + h) * 128 + d2)) * 2048 + l] = hv;
    }
  } else if (MODE == 6) {
    int bb = gr >> 11, l = gr & 2047;
    if (gc < 4096) {
      int h2 = gc >> 7, d2 = gc & 127;
      reinterpret_cast<unsigned short*>(dst)[((size_t)((bb * 32 + h2) * 2048 + l)) * 192 + d2] =
          f2bf(v * kScale);
    } else {
      reinterpret_cast<float*>(dst2)[(size_t)gr * 2048 + (gc - 4096)] = v;
    }
  }
}

// ---- m97-structure GEMM: C(MxN) = A(MxK) * Bt(NxK)^T, 128x128 tile, BK=32 ----
template <int MODE>
__global__ __launch_bounds__(256) void gemm128_kernel(const unsigned short* __restrict__ A,
                                                      const unsigned short* __restrict__ Bt,
                                                      void* __restrict__ dst, void* __restrict__ dst2,
                                                      int M, int N, int K) {
  __shared__ unsigned short lds_a[128 * 32];
  __shared__ unsigned short lds_b[128 * 32];
  int tid = threadIdx.x, lane = tid & 63, w = tid >> 6;
  int quad = lane >> 4, l16 = lane & 15;
  int wr = w >> 1, wc = w & 1;
  int mbase = blockIdx.y * 128, nbase = blockIdx.x * 128;
  f32x4 acc[4][4] = {};
  int srow0 = tid >> 2, skoff = (tid & 3) * 8;
  const size_t a_base = (size_t)(mbase + srow0) * K + skoff;
  const size_t b_base = (size_t)(nbase + srow0) * K + skoff;
  unsigned short* lba0 = &lds_a[(size_t)(w * 64) * 8];
  unsigned short* lba1 = &lds_a[(size_t)(256 + w * 64) * 8];
  unsigned short* lbb0 = &lds_b[(size_t)(w * 64) * 8];
  unsigned short* lbb1 = &lds_b[(size_t)(256 + w * 64) * 8];
  for (int k0 = 0; k0 < K; k0 += 32) {
    __syncthreads();
    gl_lds16(&A[a_base + k0], lba0);
    gl_lds16(&A[a_base + (size_t)64 * K + k0], lba1);
    gl_lds16(&Bt[b_base + k0], lbb0);
    gl_lds16(&Bt[b_base + (size_t)64 * K + k0], lbb1);
    __syncthreads();
    bf16x8 af[4], bfr[4];
#pragma unroll
    for (int i = 0; i < 4; i++) {
      af[i] = *reinterpret_cast<const bf16x8*>(&lds_a[(wr * 64 + i * 16 + l16) * 32 + quad * 8]);
      bfr[i] = *reinterpret_cast<const bf16x8*>(&lds_b[(wc * 64 + i * 16 + l16) * 32 + quad * 8]);
    }
#pragma unroll
    for (int i = 0; i < 4; i++)
#pragma unroll
      for (int j = 0; j < 4; j++) acc[i][j] = mfma16(af[i], bfr[j], acc[i][j]);
  }
#pragma unroll
  for (int i = 0; i < 4; i++)
#pragma unroll
    for (int j = 0; j < 4; j++)
#pragma unroll
      for (int r = 0; r < 4; r++) {
        int gr = mbase + wr * 64 + i * 16 + quad * 4 + r;
        int gc = nbase + wc * 64 + j * 16 + l16;
        epi_store<MODE>(dst, dst2, gr, gc, N, acc[i][j][r]);
      }
}

// ---------------- RMS norm: tmpAll fp32 (rows x 2112, col offset) -> out bf16 ----------------
__global__ __launch_bounds__(256) void rms_kernel(const float* __restrict__ in,
                                                  const float* __restrict__ w,
                                                  unsigned short* __restrict__ out, int colOff) {
  int row = blockIdx.x, tid = threadIdx.x;
  float4 v = reinterpret_cast<const float4*>(in + (size_t)row * 2112 + colOff)[tid];
  float ss = v.x * v.x + v.y * v.y + v.z * v.z + v.w * v.w;
  ss += __shfl_xor(ss, 1); ss += __shfl_xor(ss, 2); ss += __shfl_xor(ss, 4);
  ss += __shfl_xor(ss, 8); ss += __shfl_xor(ss, 16); ss += __shfl_xor(ss, 32);
  __shared__ float red[4];
  if ((tid & 63) == 0) red[tid >> 6] = ss;
  __syncthreads();
  float tot = red[0] + red[1] + red[2] + red[3];
  float rs = rsqrtf(tot * (1.0f / kDC) + 1e-6f);
  float4 wv = reinterpret_cast<const float4*>(w)[tid];
  uint2 pk;
  pk.x = (unsigned int)f2bf(v.x * rs * wv.x) | ((unsigned int)f2bf(v.y * rs * wv.y) << 16);
  pk.y = (unsigned int)f2bf(v.z * rs * wv.z) | ((unsigned int)f2bf(v.w * rs * wv.w) << 16);
  reinterpret_cast<uint2*>(out)[(size_t)row * 256 + tid] = pk;
}

// ---------------- RoPE ----------------
__device__ __forceinline__ float rope_val(float x1, float x2, int j, int l) {
  int i = j & 31;
  float inv_freq = powf(10000.0f, -(float)i * (1.0f / 32.0f));
  float ang = (float)l * inv_freq;
  float cv = cosf(ang), sv = sinf(ang);
  float rot = (j < 32) ? -x2 : x2;
  return x1 * cv + rot * sv;
}

// q_r: tmpB (4096 x 2048 fp32, col = h2*64+j) -> q_all[..., 128+j], x kScale
__global__ __launch_bounds__(256) void rope_q_kernel(const float* __restrict__ qr_raw,
                                                     unsigned short* __restrict__ q_all) {
  size_t e = (size_t)blockIdx.x * 256 + threadIdx.x;  // 4096*32*64
  int j = (int)(e & 63);
  int h2 = (int)((e >> 6) & 31);
  int bl = (int)(e >> 11);
  int l = bl & 2047, b = bl >> 11;
  float x1 = qr_raw[(size_t)bl * 2048 + h2 * 64 + j];
  float x2 = qr_raw[(size_t)bl * 2048 + h2 * 64 + (j ^ 32)];
  float val = rope_val(x1, x2, j, l) * kScale;
  q_all[((size_t)((b * 32 + h2) * 2048 + l)) * 192 + 128 + j] = f2bf(val);
}

// k_r: tmpAll cols 2048..2111 -> k_all[..., 128+j] broadcast to 16 heads
__global__ __launch_bounds__(256) void rope_k_kernel(const float* __restrict__ tmpAll,
                                                     unsigned short* __restrict__ k_all) {
  size_t e = (size_t)blockIdx.x * 256 + threadIdx.x;  // 4096*64
  int j = (int)(e & 63);
  int bl = (int)(e >> 6);
  int l = bl & 2047, b = bl >> 11;
  float x1 = tmpAll[(size_t)bl * 2112 + 2048 + j];
  float x2 = tmpAll[(size_t)bl * 2112 + 2048 + (j ^ 32)];
  unsigned short hv = f2bf(rope_val(x1, x2, j, l));
#pragma unroll
  for (int h = 0; h < 16; h++)
    k_all[((size_t)((b * 16 + h) * 2048 + l)) * 192 + 128 + j] = hv;
}

// ---------------- lambda = sigmoid(x @ W_l + b_l) ----------------
__global__ __launch_bounds__(256) void lambda_kernel(const float* __restrict__ x,
                                                     const float* __restrict__ Wl,
                                                     const float* __restrict__ bl_,
                                                     float* __restrict__ lam) {
  int row = blockIdx.x, tid = threadIdx.x;
  int c = tid & 15, g = tid >> 4;
  const float* xr = x + (size_t)row * kDim;
  float acc = 0.f;
#pragma unroll 4
  for (int i = 0; i < 128; i++) {
    int k = g + i * 16;
    acc += xr[k] * Wl[(size_t)k * 16 + c];
  }
  __shared__ float red[256];
  red[tid] = acc;
  __syncthreads();
  if (tid < 16) {
    float t = 0.f;
#pragma unroll
    for (int j = 0; j < 16; j++) t += red[j * 16 + tid];
    float z = t + bl_[tid];
    lam[(size_t)row * 16 + tid] = 1.f / (1.f + __expf(-z));
  }
}

// ---------------- flash attention v2 ----------------
// grid (qt=32, n=16, b=2), block 256 (4 waves x 16 Q-rows), both p in one block.
// No max-sub (scores bounded, scale pre-folded into q); l via ones-row in V^T.
// 64-wide K tiles; 3 barriers/tile (P write->read barrier restored in R4).
__global__ __launch_bounds__(256) void attn2_kernel(const unsigned short* __restrict__ q_all,
                                                    const unsigned short* __restrict__ k_all,
                                                    const unsigned short* __restrict__ v_allT,
                                                    unsigned short* __restrict__ attn_o) {
  __shared__ unsigned short lds_k[64 * 200];   // [kpos][feat], 25600 B
  __shared__ unsigned short lds_v[144 * 72];   // [d][kpos], rows 128..143 = ones/zeros
  __shared__ unsigned short lds_p[8 * 1152];   // per (wave,p): 16 x 72
  int qt = blockIdx.x, n = blockIdx.y, b = blockIdx.z;
  int tid = threadIdx.x, lane = tid & 63, w = tid >> 6, quad = lane >> 4, l16 = lane & 15;
  const unsigned short* k_head = k_all + ((size_t)(b * 16 + n) * 2048) * 192;
  const unsigned short* v_head = v_allT + ((size_t)(b * 16 + n) * 128) * 2048;
  const unsigned short* q0_row =
      q_all + ((size_t)(b * 32 + 2 * n) * 2048 + qt * 64 + w * 16 + l16) * 192;
  const unsigned short* q1_row = q0_row + (size_t)2048 * 192;

  bf16x8 qf0[6], qf1[6];
#pragma unroll
  for (int ks = 0; ks < 6; ks++) {
    qf0[ks] = *reinterpret_cast<const bf16x8*>(&q0_row[ks * 32 + quad * 8]);
    qf1[ks] = *reinterpret_cast<const bf16x8*>(&q1_row[ks * 32 + quad * 8]);
  }
  // ones-row (d=128) and zero rows (129..143) for the l-sum trick
  for (int idx = tid; idx < 16 * 72; idx += 256) {
    int rr = idx / 72;
    lds_v[(128 + rr) * 72 + (idx % 72)] = (rr == 0) ? (unsigned short)0x3F80 : (unsigned short)0;
  }
  f32x4 acc0[9] = {}, acc1[9] = {};
  unsigned short* pw0 = &lds_p[(size_t)(w * 2 + 0) * 1152];
  unsigned short* pw1 = &lds_p[(size_t)(w * 2 + 1) * 1152];

  for (int kt = 0; kt <= qt; kt++) {
    int pos0 = kt * 64;
    __syncthreads();
    // stage K tile 64x192
#pragma unroll
    for (int c = 0; c < 6; c++) {
      int idx = c * 256 + tid;
      int row = idx / 24, off = (idx % 24) * 8;
      *reinterpret_cast<bf16x8*>(&lds_k[row * 200 + off]) =
          *reinterpret_cast<const bf16x8*>(&k_head[(size_t)(pos0 + row) * 192 + off]);
    }
    // stage V^T tile 128x64
#pragma unroll
    for (int c = 0; c < 4; c++) {
      int idx = c * 256 + tid;
      int d = idx >> 3, po = (idx & 7) * 8;
      *reinterpret_cast<bf16x8*>(&lds_v[d * 72 + po]) =
          *reinterpret_cast<const bf16x8*>(&v_head[(size_t)d * 2048 + pos0 + po]);
    }
    __syncthreads();
    bool maskt = (kt == qt);
#pragma unroll
    for (int j = 0; j < 4; j++) {
      f32x4 s0 = {}, s1 = {};
#pragma unroll
      for (int ks = 0; ks < 6; ks++) {
        bf16x8 bK = *reinterpret_cast<const bf16x8*>(&lds_k[(j * 16 + l16) * 200 + ks * 32 + quad * 8]);
        s0 = mfma16(qf0[ks], bK, s0);
        s1 = mfma16(qf1[ks], bK, s1);
      }
#pragma unroll
      for (int r = 0; r < 4; r++) {
        bool msk = maskt && (j * 16 + l16 > w * 16 + quad * 4 + r);
        float p0 = msk ? 0.f : __expf(s0[r]);
        float p1 = msk ? 0.f : __expf(s1[r]);
        pw0[(quad * 4 + r) * 72 + j * 16 + l16] = f2bf(p0);
        pw1[(quad * 4 + r) * 72 + j * 16 + l16] = f2bf(p1);
      }
    }
    // R4: explicit barrier — same-wave ds_write->ds_read ordering is not
    // guaranteed without a wait; this also makes cross-lane visibility airtight.
    __syncthreads();
    bf16x8 pf0[2], pf1[2];
#pragma unroll
    for (int c = 0; c < 2; c++) {
      pf0[c] = *reinterpret_cast<const bf16x8*>(&pw0[l16 * 72 + c * 32 + quad * 8]);
      pf1[c] = *reinterpret_cast<const bf16x8*>(&pw1[l16 * 72 + c * 32 + quad * 8]);
    }
#pragma unroll
    for (int c = 0; c < 2; c++)
#pragma unroll
      for (int dt = 0; dt < 9; dt++) {
        bf16x8 vf = *reinterpret_cast<const bf16x8*>(&lds_v[(dt * 16 + l16) * 72 + c * 32 + quad * 8]);
        acc0[dt] = mfma16(pf0[c], vf, acc0[dt]);
        acc1[dt] = mfma16(pf1[c], vf, acc1[dt]);
      }
  }
  unsigned short* o0 = attn_o + ((size_t)(b * 32 + 2 * n) * 2048 + qt * 64 + w * 16) * 128;
  unsigned short* o1 = o0 + (size_t)2048 * 128;
#pragma unroll
  for (int r = 0; r < 4; r++) {
    float li0 = __shfl(acc0[8][r], lane & 48);  // col 128 (= row-sum) lives in l16==0
    float li1 = __shfl(acc1[8][r], lane & 48);
    float inv0 = 1.f / li0, inv1 = 1.f / li1;
    int row = quad * 4 + r;
#pragma unroll
    for (int dt = 0; dt < 8; dt++) {
      o0[(size_t)row * 128 + dt * 16 + l16] = f2bf(acc0[dt][r] * inv0);
      o1[(size_t)row * 128 + dt * 16 + l16] = f2bf(acc1[dt][r] * inv1);
    }
  }
}

// ---------------- combine: attn1 - lam*attn2 -> bf16 [bl][n*128+d] ----------------
__global__ __launch_bounds__(256) void combine_kernel(const unsigned short* __restrict__ attn_o,
                                                      const float* __restrict__ lam,
                                                      unsigned short* __restrict__ out) {
  size_t e = (size_t)blockIdx.x * 256 + threadIdx.x;  // 4096*2048
  int c = (int)(e & 2047);
  int bl = (int)(e >> 11);
  int n = c >> 7, d = c & 127;
  int b = bl >> 11, l = bl & 2047;
  size_t base = ((size_t)((b * 32 + n * 2) * 2048 + l)) * 128 + d;
  float a1 = bf2f(attn_o[base]);
  float a2 = bf2f(attn_o[base + (size_t)2048 * 128]);
  float lm = lam[(size_t)bl * 16 + n];
  out[e] = f2bf(a1 - lm * a2);
}

}  // namespace

extern "C" void kernel_launch(void* const* d_in, const int* in_sizes, int n_in,
                              void* d_out, int out_size, void* d_ws, size_t ws_size,
                              hipStream_t stream) {
  const float* x      = (const float*)d_in[0];
  const float* W_DKV  = (const float*)d_in[1];
  const float* kvnw   = (const float*)d_in[2];
  const float* W_UK   = (const float*)d_in[3];
  const float* W_UV   = (const float*)d_in[4];
  const float* W_DQ   = (const float*)d_in[5];
  const float* qnw    = (const float*)d_in[6];
  const float* W_UQ   = (const float*)d_in[7];
  const float* W_QR   = (const float*)d_in[8];
  const float* W_KR   = (const float*)d_in[9];
  const float* W_lw   = (const float*)d_in[10];
  const float* W_lb   = (const float*)d_in[11];
  const float* W_out  = (const float*)d_in[12];
  float* out = (float*)d_out;

  // ---- workspace carve ----
  char* ws = (char*)d_ws;
  size_t off = 0;
  auto alloc = [&](size_t bytes) { char* p = ws + off; off += (bytes + 255) & ~(size_t)255; return p; };
  unsigned short* xb     = (unsigned short*)alloc((size_t)4096 * 2048 * 2);
  unsigned short* wd_cat = (unsigned short*)alloc((size_t)2176 * 2048 * 2);  // [DKV|DQ|KR|pad] x K
  unsigned short* wu_cat = (unsigned short*)alloc((size_t)4096 * 1024 * 2);  // [UK|UV] x K
  unsigned short* wuqr   = (unsigned short*)alloc((size_t)6144 * 1024 * 2);  // [UQ|QR] x K
  unsigned short* wout   = (unsigned short*)alloc((size_t)2048 * 2048 * 2);
  unsigned short* ckv    = (unsigned short*)alloc((size_t)4096 * 1024 * 2);
  unsigned short* cq     = (unsigned short*)alloc((size_t)4096 * 1024 * 2);
  unsigned short* k_all  = (unsigned short*)alloc((size_t)2 * 16 * 2048 * 192 * 2);
  unsigned short* v_allT = (unsigned short*)alloc((size_t)2 * 16 * 128 * 2048 * 2);
  unsigned short* q_all  = (unsigned short*)alloc((size_t)2 * 32 * 2048 * 192 * 2);
  unsigned short* attn_o = (unsigned short*)alloc((size_t)2 * 32 * 2048 * 128 * 2);
  unsigned short* attn_b = (unsigned short*)alloc((size_t)4096 * 2048 * 2);
  float* lam             = (float*)alloc((size_t)4096 * 16 * 4);
  float* tmpAll          = (float*)alloc((size_t)4096 * 2112 * 4);
  float* tmpB            = tmpAll;  // aliased: tmpAll fully consumed before GEMM<6> writes tmpB
  (void)ws_size; (void)in_sizes; (void)n_in; (void)out_size;

  // ---- convert x; weights transposed to NxK bf16, concatenated along N ----
  hipLaunchKernelGGL(conv_bf16_kernel, dim3(8192), dim3(256), 0, stream, x, xb, 2097152);
  hipLaunchKernelGGL(transpose_conv_kernel, dim3(32, 64), dim3(256), 0, stream, W_DKV, wd_cat, 2048, 1024);
  hipLaunchKernelGGL(transpose_conv_kernel, dim3(32, 64), dim3(256), 0, stream, W_DQ,
                     wd_cat + (size_t)1024 * 2048, 2048, 1024);
  hipLaunchKernelGGL(transpose_conv_kernel, dim3(2, 64), dim3(256), 0, stream, W_KR,
                     wd_cat + (size_t)2048 * 2048, 2048, 64);
  hipLaunchKernelGGL(zero_bf16_kernel, dim3(64), dim3(256), 0, stream,
                     wd_cat + (size_t)2112 * 2048, 16384);  // pad rows [2112,2176)
  hipLaunchKernelGGL(transpose_conv_kernel, dim3(64, 32), dim3(256), 0, stream, W_UK, wu_cat, 1024, 2048);
  hipLaunchKernelGGL(transpose_conv_kernel, dim3(64, 32), dim3(256), 0, stream, W_UV,
                     wu_cat + (size_t)2048 * 1024, 1024, 2048);
  hipLaunchKernelGGL(transpose_conv_kernel, dim3(128, 32), dim3(256), 0, stream, W_UQ, wuqr, 1024, 4096);
  hipLaunchKernelGGL(transpose_conv_kernel, dim3(64, 32), dim3(256), 0, stream, W_QR,
                     wuqr + (size_t)4096 * 1024, 1024, 2048);
  hipLaunchKernelGGL(transpose_conv_kernel, dim3(64, 64), dim3(256), 0, stream, W_out, wout, 2048, 2048);

  // ---- fused down-proj (DKV|DQ|KR): 544 blocks ----
  hipLaunchKernelGGL(gemm128_kernel<4>, dim3(17, 32), dim3(256), 0, stream,
                     xb, wd_cat, tmpAll, (void*)nullptr, 4096, 2176, 2048);
  hipLaunchKernelGGL(rms_kernel, dim3(4096), dim3(256), 0, stream, tmpAll, kvnw, ckv, 0);
  hipLaunchKernelGGL(rms_kernel, dim3(4096), dim3(256), 0, stream, tmpAll, qnw, cq, 1024);
  hipLaunchKernelGGL(rope_k_kernel, dim3(1024), dim3(256), 0, stream, tmpAll, k_all);

  // ---- fused up-projections: UK|UV (1024 blocks), UQ|QR (1536 blocks) ----
  hipLaunchKernelGGL(gemm128_kernel<5>, dim3(32, 32), dim3(256), 0, stream,
                     ckv, wu_cat, k_all, v_allT, 4096, 4096, 1024);
  hipLaunchKernelGGL(gemm128_kernel<6>, dim3(48, 32), dim3(256), 0, stream,
                     cq, wuqr, q_all, tmpB, 4096, 6144, 1024);  // tmpB clobbers tmpAll (consumed)
  hipLaunchKernelGGL(rope_q_kernel, dim3(32768), dim3(256), 0, stream, tmpB, q_all);
  hipLaunchKernelGGL(lambda_kernel, dim3(4096), dim3(256), 0, stream, x, W_lw, W_lb, lam);

  // ---- attention (p-merged, 64-wide K tiles) ----
  hipLaunchKernelGGL(attn2_kernel, dim3(32, 16, 2), dim3(256), 0, stream,
                     q_all, k_all, v_allT, attn_o);

  // ---- combine + output projection (512 blocks) ----
  hipLaunchKernelGGL(combine_kernel, dim3(32768), dim3(256), 0, stream, attn_o, lam, attn_b);
  hipLaunchKernelGGL(gemm128_kernel<0>, dim3(16, 32), dim3(256), 0, stream,
                     attn_b, wout, out, (void*)nullptr, 4096, 2048, 2048);
}

// Round 5
// 788.102 us; speedup vs baseline: 1.4264x; 1.1154x over previous
//
#include <hip/hip_runtime.h>
#include <cstddef>
#include <cstdint>

// DiffMLA attention, MI355X.
// R5: attention v3 — double-buffered 32-wide K/V tiles via async global_load_lds,
// XOR-swizzled K/V layouts (DMA-contiguous AND conflict-free ds_read_b128),
// 1 barrier/tile, wave-local lgkmcnt(0) for the P round-trip, 3 blocks/CU.
// GEMM chain unchanged from R4.

namespace {

constexpr int kDC = 1024, kDim = 2048;
constexpr float kScale = 0.07216878364870323f;  // 1/sqrt(192)

typedef __bf16 bf16x8 __attribute__((ext_vector_type(8)));
typedef float f32x4 __attribute__((ext_vector_type(4)));

__device__ __forceinline__ unsigned short f2bf(float f) {
  union { float f; unsigned int u; } v; v.f = f;
  unsigned int r = v.u + 0x7FFFu + ((v.u >> 16) & 1u);
  return (unsigned short)(r >> 16);
}
__device__ __forceinline__ float bf2f(unsigned short h) {
  union { unsigned int u; float f; } v; v.u = ((unsigned int)h) << 16;
  return v.f;
}
__device__ __forceinline__ f32x4 mfma16(bf16x8 a, bf16x8 b, f32x4 c) {
  return __builtin_amdgcn_mfma_f32_16x16x32_bf16(a, b, c, 0, 0, 0);
}
__device__ __forceinline__ void gl_lds16(const void* g, void* l) {
  __builtin_amdgcn_global_load_lds(
      (const __attribute__((address_space(1))) unsigned int*)g,
      (__attribute__((address_space(3))) unsigned int*)l, 16, 0, 0);
}
__device__ __forceinline__ void wait_lgkm0() {
  asm volatile("s_waitcnt lgkmcnt(0)" ::: "memory");
}

// ---------------- convert f32 -> bf16 ----------------
__global__ __launch_bounds__(256) void conv_bf16_kernel(const float* __restrict__ in,
                                                        unsigned short* __restrict__ out, int n4) {
  int e = blockIdx.x * 256 + threadIdx.x;
  if (e >= n4) return;
  float4 v = reinterpret_cast<const float4*>(in)[e];
  uint2 pk;
  pk.x = (unsigned int)f2bf(v.x) | ((unsigned int)f2bf(v.y) << 16);
  pk.y = (unsigned int)f2bf(v.z) | ((unsigned int)f2bf(v.w) << 16);
  reinterpret_cast<uint2*>(out)[e] = pk;
}

// ---------------- zero-fill bf16 region ----------------
__global__ __launch_bounds__(256) void zero_bf16_kernel(unsigned short* __restrict__ out, int n8) {
  int e = blockIdx.x * 256 + threadIdx.x;
  if (e >= n8) return;
  reinterpret_cast<uint4*>(out)[e] = uint4{0, 0, 0, 0};
}

// ------------- transpose+convert: in (K x N) f32 -> out (N x K) bf16 -------------
__global__ __launch_bounds__(256) void transpose_conv_kernel(const float* __restrict__ in,
                                                             unsigned short* __restrict__ out,
                                                             int K, int N) {
  __shared__ float t[32][33];
  int n0 = blockIdx.x * 32, k0 = blockIdx.y * 32;
  int tx = threadIdx.x & 31, ty = threadIdx.x >> 5;
#pragma unroll
  for (int i = 0; i < 4; i++) t[ty + i * 8][tx] = in[(size_t)(k0 + ty + i * 8) * N + n0 + tx];
  __syncthreads();
#pragma unroll
  for (int i = 0; i < 4; i++)
    out[(size_t)(n0 + ty + i * 8) * K + k0 + tx] = f2bf(t[tx][ty + i * 8]);
}

// ---------------- epilogue ----------------
// MODE 0: fp32 row-major C (stride N)
// MODE 4: fused down-proj: fp32 stride 2112; cols 0..1023 c_kv | 1024..2047 c_q
//         | 2048..2111 k_r | >=2112 dropped
// MODE 5: fused UK|UV: gc<2048 -> k_all pack (XOR-swizzled d); else v_allT pack (XOR-swizzled l)
// MODE 6: fused UQ|QR: gc<4096 -> q_all pack (x kScale); else tmpB fp32 (stride 2048)
template <int MODE>
__device__ __forceinline__ void epi_store(void* dst, void* dst2, int gr, int gc, int N, float v) {
  if (MODE == 0) {
    reinterpret_cast<float*>(dst)[(size_t)gr * N + gc] = v;
  } else if (MODE == 4) {
    if (gc < 2112) reinterpret_cast<float*>(dst)[(size_t)gr * 2112 + gc] = v;
  } else if (MODE == 5) {
    int bb = gr >> 11, l = gr & 2047;
    unsigned short hv = f2bf(v);
    if (gc < 2048) {
      int h = gc >> 7, d2 = gc & 127;
      int d2s = d2 ^ ((l & 7) << 3);  // K swizzle: 16B group XOR by row&7
      reinterpret_cast<unsigned short*>(dst)[((size_t)((bb * 16 + h) * 2048 + l)) * 192 + d2s] = hv;
    } else {
      int g2 = gc - 2048, h = g2 >> 7, d2 = g2 & 127;
      int ls = l ^ (((d2 >> 1) & 3) << 3);  // V swizzle: pos group XOR by (d>>1)&3
      reinterpret_cast<unsigned short*>(dst2)[((size_t)((bb * 16 + h) * 128 + d2)) * 2048 + ls] = hv;
    }
  } else if (MODE == 6) {
    int bb = gr >> 11, l = gr & 2047;
    if (gc < 4096) {
      int h2 = gc >> 7, d2 = gc & 127;
      reinterpret_cast<unsigned short*>(dst)[((size_t)((bb * 32 + h2) * 2048 + l)) * 192 + d2] =
          f2bf(v * kScale);
    } else {
      reinterpret_cast<float*>(dst2)[(size_t)gr * 2048 + (gc - 4096)] = v;
    }
  }
}

// ---- m97-structure GEMM: C(MxN) = A(MxK) * Bt(NxK)^T, 128x128 tile, BK=32 ----
template <int MODE>
__global__ __launch_bounds__(256) void gemm128_kernel(const unsigned short* __restrict__ A,
                                                      const unsigned short* __restrict__ Bt,
                                                      void* __restrict__ dst, void* __restrict__ dst2,
                                                      int M, int N, int K) {
  __shared__ unsigned short lds_a[128 * 32];
  __shared__ unsigned short lds_b[128 * 32];
  int tid = threadIdx.x, lane = tid & 63, w = tid >> 6;
  int quad = lane >> 4, l16 = lane & 15;
  int wr = w >> 1, wc = w & 1;
  int mbase = blockIdx.y * 128, nbase = blockIdx.x * 128;
  f32x4 acc[4][4] = {};
  int srow0 = tid >> 2, skoff = (tid & 3) * 8;
  const size_t a_base = (size_t)(mbase + srow0) * K + skoff;
  const size_t b_base = (size_t)(nbase + srow0) * K + skoff;
  unsigned short* lba0 = &lds_a[(size_t)(w * 64) * 8];
  unsigned short* lba1 = &lds_a[(size_t)(256 + w * 64) * 8];
  unsigned short* lbb0 = &lds_b[(size_t)(w * 64) * 8];
  unsigned short* lbb1 = &lds_b[(size_t)(256 + w * 64) * 8];
  for (int k0 = 0; k0 < K; k0 += 32) {
    __syncthreads();
    gl_lds16(&A[a_base + k0], lba0);
    gl_lds16(&A[a_base + (size_t)64 * K + k0], lba1);
    gl_lds16(&Bt[b_base + k0], lbb0);
    gl_lds16(&Bt[b_base + (size_t)64 * K + k0], lbb1);
    __syncthreads();
    bf16x8 af[4], bfr[4];
#pragma unroll
    for (int i = 0; i < 4; i++) {
      af[i] = *reinterpret_cast<const bf16x8*>(&lds_a[(wr * 64 + i * 16 + l16) * 32 + quad * 8]);
      bfr[i] = *reinterpret_cast<const bf16x8*>(&lds_b[(wc * 64 + i * 16 + l16) * 32 + quad * 8]);
    }
#pragma unroll
    for (int i = 0; i < 4; i++)
#pragma unroll
      for (int j = 0; j < 4; j++) acc[i][j] = mfma16(af[i], bfr[j], acc[i][j]);
  }
#pragma unroll
  for (int i = 0; i < 4; i++)
#pragma unroll
    for (int j = 0; j < 4; j++)
#pragma unroll
      for (int r = 0; r < 4; r++) {
        int gr = mbase + wr * 64 + i * 16 + quad * 4 + r;
        int gc = nbase + wc * 64 + j * 16 + l16;
        epi_store<MODE>(dst, dst2, gr, gc, N, acc[i][j][r]);
      }
}

// ---------------- RMS norm ----------------
__global__ __launch_bounds__(256) void rms_kernel(const float* __restrict__ in,
                                                  const float* __restrict__ w,
                                                  unsigned short* __restrict__ out, int colOff) {
  int row = blockIdx.x, tid = threadIdx.x;
  float4 v = reinterpret_cast<const float4*>(in + (size_t)row * 2112 + colOff)[tid];
  float ss = v.x * v.x + v.y * v.y + v.z * v.z + v.w * v.w;
  ss += __shfl_xor(ss, 1); ss += __shfl_xor(ss, 2); ss += __shfl_xor(ss, 4);
  ss += __shfl_xor(ss, 8); ss += __shfl_xor(ss, 16); ss += __shfl_xor(ss, 32);
  __shared__ float red[4];
  if ((tid & 63) == 0) red[tid >> 6] = ss;
  __syncthreads();
  float tot = red[0] + red[1] + red[2] + red[3];
  float rs = rsqrtf(tot * (1.0f / kDC) + 1e-6f);
  float4 wv = reinterpret_cast<const float4*>(w)[tid];
  uint2 pk;
  pk.x = (unsigned int)f2bf(v.x * rs * wv.x) | ((unsigned int)f2bf(v.y * rs * wv.y) << 16);
  pk.y = (unsigned int)f2bf(v.z * rs * wv.z) | ((unsigned int)f2bf(v.w * rs * wv.w) << 16);
  reinterpret_cast<uint2*>(out)[(size_t)row * 256 + tid] = pk;
}

// ---------------- RoPE ----------------
__device__ __forceinline__ float rope_val(float x1, float x2, int j, int l) {
  int i = j & 31;
  float inv_freq = powf(10000.0f, -(float)i * (1.0f / 32.0f));
  float ang = (float)l * inv_freq;
  float cv = cosf(ang), sv = sinf(ang);
  float rot = (j < 32) ? -x2 : x2;
  return x1 * cv + rot * sv;
}

// q_r -> q_all[..., 128+j], x kScale (q_all unswizzled)
__global__ __launch_bounds__(256) void rope_q_kernel(const float* __restrict__ qr_raw,
                                                     unsigned short* __restrict__ q_all) {
  size_t e = (size_t)blockIdx.x * 256 + threadIdx.x;  // 4096*32*64
  int j = (int)(e & 63);
  int h2 = (int)((e >> 6) & 31);
  int bl = (int)(e >> 11);
  int l = bl & 2047, b = bl >> 11;
  float x1 = qr_raw[(size_t)bl * 2048 + h2 * 64 + j];
  float x2 = qr_raw[(size_t)bl * 2048 + h2 * 64 + (j ^ 32)];
  float val = rope_val(x1, x2, j, l) * kScale;
  q_all[((size_t)((b * 32 + h2) * 2048 + l)) * 192 + 128 + j] = f2bf(val);
}

// k_r -> k_all[..., 128 + (j ^ swz)] broadcast to 16 heads (K swizzle applied)
__global__ __launch_bounds__(256) void rope_k_kernel(const float* __restrict__ tmpAll,
                                                     unsigned short* __restrict__ k_all) {
  size_t e = (size_t)blockIdx.x * 256 + threadIdx.x;  // 4096*64
  int j = (int)(e & 63);
  int bl = (int)(e >> 6);
  int l = bl & 2047, b = bl >> 11;
  float x1 = tmpAll[(size_t)bl * 2112 + 2048 + j];
  float x2 = tmpAll[(size_t)bl * 2112 + 2048 + (j ^ 32)];
  unsigned short hv = f2bf(rope_val(x1, x2, j, l));
  int js = j ^ ((l & 7) << 3);  // same 16B-group swizzle as MODE 5 K pack
#pragma unroll
  for (int h = 0; h < 16; h++)
    k_all[((size_t)((b * 16 + h) * 2048 + l)) * 192 + 128 + js] = hv;
}

// ---------------- lambda = sigmoid(x @ W_l + b_l) ----------------
__global__ __launch_bounds__(256) void lambda_kernel(const float* __restrict__ x,
                                                     const float* __restrict__ Wl,
                                                     const float* __restrict__ bl_,
                                                     float* __restrict__ lam) {
  int row = blockIdx.x, tid = threadIdx.x;
  int c = tid & 15, g = tid >> 4;
  const float* xr = x + (size_t)row * kDim;
  float acc = 0.f;
#pragma unroll 4
  for (int i = 0; i < 128; i++) {
    int k = g + i * 16;
    acc += xr[k] * Wl[(size_t)k * 16 + c];
  }
  __shared__ float red[256];
  red[tid] = acc;
  __syncthreads();
  if (tid < 16) {
    float t = 0.f;
#pragma unroll
    for (int j = 0; j < 16; j++) t += red[j * 16 + tid];
    float z = t + bl_[tid];
    lam[(size_t)row * 16 + tid] = 1.f / (1.f + __expf(-z));
  }
}

// ---------------- flash attention v3 ----------------
// grid (qt=32, n=16, b=2), block 256 (4 waves x 16 Q-rows), both p per block.
// 32-wide K/V tiles, double-buffered, staged via global_load_lds (async DMA).
// One __syncthreads per tile: drains prev DMA (which overlapped compute) and
// fences buffer reuse. K/V global layouts XOR-swizzled for conflict-free reads.
__global__ __launch_bounds__(256, 3) void attn3_kernel(const unsigned short* __restrict__ q_all,
                                                       const unsigned short* __restrict__ k_all,
                                                       const unsigned short* __restrict__ v_allT,
                                                       unsigned short* __restrict__ attn_o) {
  __shared__ unsigned short lds_k[2][32 * 192];  // 24576 B, DMA-contiguous, swizzled
  __shared__ unsigned short lds_v[2][128 * 32];  // 16384 B, DMA-contiguous, swizzled
  __shared__ unsigned short lds_p[8 * 640];      // per (wave,p): 16x40, 10240 B
  __shared__ unsigned short lds_ones[16 * 32];   // row 0 = 1.0 (l-sum trick), 1024 B
  int qt = blockIdx.x, n = blockIdx.y, b = blockIdx.z;
  int tid = threadIdx.x, lane = tid & 63, w = tid >> 6, quad = lane >> 4, l16 = lane & 15;
  const unsigned short* k_head = k_all + ((size_t)(b * 16 + n) * 2048) * 192;
  const unsigned short* v_head = v_allT + ((size_t)(b * 16 + n) * 128) * 2048;
  const unsigned short* q0_row =
      q_all + ((size_t)(b * 32 + 2 * n) * 2048 + qt * 64 + w * 16 + l16) * 192;
  const unsigned short* q1_row = q0_row + (size_t)2048 * 192;

  bf16x8 qf0[6], qf1[6];
#pragma unroll
  for (int ks = 0; ks < 6; ks++) {
    qf0[ks] = *reinterpret_cast<const bf16x8*>(&q0_row[ks * 32 + quad * 8]);
    qf1[ks] = *reinterpret_cast<const bf16x8*>(&q1_row[ks * 32 + quad * 8]);
  }
  // ones rows: row 0 = 1.0, rows 1..15 = 0
  for (int idx = tid; idx < 512; idx += 256)
    lds_ones[idx] = (idx < 32) ? (unsigned short)0x3F80 : (unsigned short)0;

  f32x4 acc0[9] = {}, acc1[9] = {};
  unsigned short* pw0 = &lds_p[(w * 2 + 0) * 640];
  unsigned short* pw1 = &lds_p[(w * 2 + 1) * 640];
  int qlo = qt * 64 + w * 16;
  int nt = 2 * qt + 2;

  // stage(tile, buf): 3 K-chunks + 2 V-chunks of 1024B per wave, async.
  auto stage = [&](int pos0, int buf) {
    const unsigned short* kg = k_head + (size_t)pos0 * 192 + w * 1536 + lane * 8;
    unsigned short* kl = &lds_k[buf][w * 1536];
    gl_lds16(kg, kl);
    gl_lds16(kg + 512, kl + 512);
    gl_lds16(kg + 1024, kl + 1024);
    const unsigned short* vg =
        v_head + (size_t)(w * 32 + (lane >> 2)) * 2048 + pos0 + (lane & 3) * 8;
    unsigned short* vl = &lds_v[buf][w * 1024];
    gl_lds16(vg, vl);
    gl_lds16(vg + (size_t)16 * 2048, vl + 512);
  };

  stage(0, 0);
  for (int kt = 0; kt < nt; kt++) {
    int cur = kt & 1;
    int pos0 = kt * 32;
    __syncthreads();  // tile-cur DMA (issued last iter, overlapped compute) done on all
                      // waves; everyone finished reading buf cur^1 -> safe to overwrite
    if (kt + 1 < nt) stage((kt + 1) * 32, cur ^ 1);  // async, overlaps compute below
    if (pos0 <= qlo + 15) {
      const unsigned short* kb = &lds_k[cur][0];
      const unsigned short* vb = &lds_v[cur][0];
      bool needmask = (pos0 + 31 > qlo);
      int ksw = (l16 & 7) << 3;          // K read swizzle
      int vsw = (l16 >> 1) & 3;          // V read swizzle (group XOR)
#pragma unroll
      for (int j = 0; j < 2; j++) {
        f32x4 s0 = {}, s1 = {};
#pragma unroll
        for (int ks = 0; ks < 6; ks++) {
          bf16x8 bK = *reinterpret_cast<const bf16x8*>(
              &kb[(j * 16 + l16) * 192 + ((ks * 32 + quad * 8) ^ ksw)]);
          s0 = mfma16(qf0[ks], bK, s0);
          s1 = mfma16(qf1[ks], bK, s1);
        }
#pragma unroll
        for (int r = 0; r < 4; r++) {
          bool msk = needmask && (pos0 + j * 16 + l16 > qlo + quad * 4 + r);
          float p0 = msk ? 0.f : __expf(s0[r]);
          float p1 = msk ? 0.f : __expf(s1[r]);
          pw0[(quad * 4 + r) * 40 + j * 16 + l16] = f2bf(p0);
          pw1[(quad * 4 + r) * 40 + j * 16 + l16] = f2bf(p1);
        }
      }
      wait_lgkm0();  // wave-local: P ds_writes committed before P ds_reads
      bf16x8 pf0 = *reinterpret_cast<const bf16x8*>(&pw0[l16 * 40 + quad * 8]);
      bf16x8 pf1 = *reinterpret_cast<const bf16x8*>(&pw1[l16 * 40 + quad * 8]);
#pragma unroll
      for (int dt = 0; dt < 8; dt++) {
        bf16x8 vf = *reinterpret_cast<const bf16x8*>(
            &vb[(dt * 16 + l16) * 32 + ((quad ^ vsw) * 8)]);
        acc0[dt] = mfma16(pf0, vf, acc0[dt]);
        acc1[dt] = mfma16(pf1, vf, acc1[dt]);
      }
      bf16x8 vone = *reinterpret_cast<const bf16x8*>(&lds_ones[l16 * 32 + quad * 8]);
      acc0[8] = mfma16(pf0, vone, acc0[8]);
      acc1[8] = mfma16(pf1, vone, acc1[8]);
    }
  }
  unsigned short* o0 = attn_o + ((size_t)(b * 32 + 2 * n) * 2048 + qt * 64 + w * 16) * 128;
  unsigned short* o1 = o0 + (size_t)2048 * 128;
#pragma unroll
  for (int r = 0; r < 4; r++) {
    float li0 = __shfl(acc0[8][r], lane & 48);  // row-sum lives in l16==0 of each quad
    float li1 = __shfl(acc1[8][r], lane & 48);
    float inv0 = 1.f / li0, inv1 = 1.f / li1;
    int row = quad * 4 + r;
#pragma unroll
    for (int dt = 0; dt < 8; dt++) {
      o0[(size_t)row * 128 + dt * 16 + l16] = f2bf(acc0[dt][r] * inv0);
      o1[(size_t)row * 128 + dt * 16 + l16] = f2bf(acc1[dt][r] * inv1);
    }
  }
}

// ---------------- combine: attn1 - lam*attn2 -> bf16 [bl][n*128+d] ----------------
__global__ __launch_bounds__(256) void combine_kernel(const unsigned short* __restrict__ attn_o,
                                                      const float* __restrict__ lam,
                                                      unsigned short* __restrict__ out) {
  size_t e = (size_t)blockIdx.x * 256 + threadIdx.x;  // 4096*2048
  int c = (int)(e & 2047);
  int bl = (int)(e >> 11);
  int n = c >> 7, d = c & 127;
  int b = bl >> 11, l = bl & 2047;
  size_t base = ((size_t)((b * 32 + n * 2) * 2048 + l)) * 128 + d;
  float a1 = bf2f(attn_o[base]);
  float a2 = bf2f(attn_o[base + (size_t)2048 * 128]);
  float lm = lam[(size_t)bl * 16 + n];
  out[e] = f2bf(a1 - lm * a2);
}

}  // namespace

extern "C" void kernel_launch(void* const* d_in, const int* in_sizes, int n_in,
                              void* d_out, int out_size, void* d_ws, size_t ws_size,
                              hipStream_t stream) {
  const float* x      = (const float*)d_in[0];
  const float* W_DKV  = (const float*)d_in[1];
  const float* kvnw   = (const float*)d_in[2];
  const float* W_UK   = (const float*)d_in[3];
  const float* W_UV   = (const float*)d_in[4];
  const float* W_DQ   = (const float*)d_in[5];
  const float* qnw    = (const float*)d_in[6];
  const float* W_UQ   = (const float*)d_in[7];
  const float* W_QR   = (const float*)d_in[8];
  const float* W_KR   = (const float*)d_in[9];
  const float* W_lw   = (const float*)d_in[10];
  const float* W_lb   = (const float*)d_in[11];
  const float* W_out  = (const float*)d_in[12];
  float* out = (float*)d_out;

  // ---- workspace carve ----
  char* ws = (char*)d_ws;
  size_t off = 0;
  auto alloc = [&](size_t bytes) { char* p = ws + off; off += (bytes + 255) & ~(size_t)255; return p; };
  unsigned short* xb     = (unsigned short*)alloc((size_t)4096 * 2048 * 2);
  unsigned short* wd_cat = (unsigned short*)alloc((size_t)2176 * 2048 * 2);  // [DKV|DQ|KR|pad] x K
  unsigned short* wu_cat = (unsigned short*)alloc((size_t)4096 * 1024 * 2);  // [UK|UV] x K
  unsigned short* wuqr   = (unsigned short*)alloc((size_t)6144 * 1024 * 2);  // [UQ|QR] x K
  unsigned short* wout   = (unsigned short*)alloc((size_t)2048 * 2048 * 2);
  unsigned short* ckv    = (unsigned short*)alloc((size_t)4096 * 1024 * 2);
  unsigned short* cq     = (unsigned short*)alloc((size_t)4096 * 1024 * 2);
  unsigned short* k_all  = (unsigned short*)alloc((size_t)2 * 16 * 2048 * 192 * 2);
  unsigned short* v_allT = (unsigned short*)alloc((size_t)2 * 16 * 128 * 2048 * 2);
  unsigned short* q_all  = (unsigned short*)alloc((size_t)2 * 32 * 2048 * 192 * 2);
  unsigned short* attn_o = (unsigned short*)alloc((size_t)2 * 32 * 2048 * 128 * 2);
  unsigned short* attn_b = (unsigned short*)alloc((size_t)4096 * 2048 * 2);
  float* lam             = (float*)alloc((size_t)4096 * 16 * 4);
  float* tmpAll          = (float*)alloc((size_t)4096 * 2112 * 4);
  float* tmpB            = tmpAll;  // aliased: tmpAll fully consumed before GEMM<6> writes tmpB
  (void)ws_size; (void)in_sizes; (void)n_in; (void)out_size;

  // ---- convert x; weights transposed to NxK bf16, concatenated along N ----
  hipLaunchKernelGGL(conv_bf16_kernel, dim3(8192), dim3(256), 0, stream, x, xb, 2097152);
  hipLaunchKernelGGL(transpose_conv_kernel, dim3(32, 64), dim3(256), 0, stream, W_DKV, wd_cat, 2048, 1024);
  hipLaunchKernelGGL(transpose_conv_kernel, dim3(32, 64), dim3(256), 0, stream, W_DQ,
                     wd_cat + (size_t)1024 * 2048, 2048, 1024);
  hipLaunchKernelGGL(transpose_conv_kernel, dim3(2, 64), dim3(256), 0, stream, W_KR,
                     wd_cat + (size_t)2048 * 2048, 2048, 64);
  hipLaunchKernelGGL(zero_bf16_kernel, dim3(64), dim3(256), 0, stream,
                     wd_cat + (size_t)2112 * 2048, 16384);  // pad rows [2112,2176)
  hipLaunchKernelGGL(transpose_conv_kernel, dim3(64, 32), dim3(256), 0, stream, W_UK, wu_cat, 1024, 2048);
  hipLaunchKernelGGL(transpose_conv_kernel, dim3(64, 32), dim3(256), 0, stream, W_UV,
                     wu_cat + (size_t)2048 * 1024, 1024, 2048);
  hipLaunchKernelGGL(transpose_conv_kernel, dim3(128, 32), dim3(256), 0, stream, W_UQ, wuqr, 1024, 4096);
  hipLaunchKernelGGL(transpose_conv_kernel, dim3(64, 32), dim3(256), 0, stream, W_QR,
                     wuqr + (size_t)4096 * 1024, 1024, 2048);
  hipLaunchKernelGGL(transpose_conv_kernel, dim3(64, 64), dim3(256), 0, stream, W_out, wout, 2048, 2048);

  // ---- fused down-proj (DKV|DQ|KR): 544 blocks ----
  hipLaunchKernelGGL(gemm128_kernel<4>, dim3(17, 32), dim3(256), 0, stream,
                     xb, wd_cat, tmpAll, (void*)nullptr, 4096, 2176, 2048);
  hipLaunchKernelGGL(rms_kernel, dim3(4096), dim3(256), 0, stream, tmpAll, kvnw, ckv, 0);
  hipLaunchKernelGGL(rms_kernel, dim3(4096), dim3(256), 0, stream, tmpAll, qnw, cq, 1024);
  hipLaunchKernelGGL(rope_k_kernel, dim3(1024), dim3(256), 0, stream, tmpAll, k_all);

  // ---- fused up-projections: UK|UV (1024 blocks), UQ|QR (1536 blocks) ----
  hipLaunchKernelGGL(gemm128_kernel<5>, dim3(32, 32), dim3(256), 0, stream,
                     ckv, wu_cat, k_all, v_allT, 4096, 4096, 1024);
  hipLaunchKernelGGL(gemm128_kernel<6>, dim3(48, 32), dim3(256), 0, stream,
                     cq, wuqr, q_all, tmpB, 4096, 6144, 1024);  // tmpB clobbers tmpAll (consumed)
  hipLaunchKernelGGL(rope_q_kernel, dim3(32768), dim3(256), 0, stream, tmpB, q_all);
  hipLaunchKernelGGL(lambda_kernel, dim3(4096), dim3(256), 0, stream, x, W_lw, W_lb, lam);

  // ---- attention v3 (double-buffered async DMA) ----
  hipLaunchKernelGGL(attn3_kernel, dim3(32, 16, 2), dim3(256), 0, stream,
                     q_all, k_all, v_allT, attn_o);

  // ---- combine + output projection (512 blocks) ----
  hipLaunchKernelGGL(combine_kernel, dim3(32768), dim3(256), 0, stream, attn_o, lam, attn_b);
  hipLaunchKernelGGL(gemm128_kernel<0>, dim3(16, 32), dim3(256), 0, stream,
                     attn_b, wout, out, (void*)nullptr, 4096, 2048, 2048);
}

// Round 6
// 735.613 us; speedup vs baseline: 1.5282x; 1.0714x over previous
//
#include <hip/hip_runtime.h>
#include <cstddef>
#include <cstdint>

// DiffMLA attention, MI355X.
// R6: VALU/epilogue cuts — native v_cvt bf16 conversions (f2bf was 4 insts),
// lambda GEMV folded into the fused down-proj's pad columns (free), tmpB bf16,
// combine vectorized x8. Attention structure unchanged from R5.

namespace {

constexpr int kDC = 1024, kDim = 2048;
constexpr float kScale = 0.07216878364870323f;  // 1/sqrt(192)
constexpr int kTA = 2128;  // tmpAll row stride (c_kv 1024 | c_q 1024 | k_r 64 | lam 16)

typedef __bf16 bf16x8 __attribute__((ext_vector_type(8)));
typedef float f32x4 __attribute__((ext_vector_type(4)));

__device__ __forceinline__ unsigned short f2bf(float f) {
  __bf16 h = (__bf16)f;  // native v_cvt_pk_bf16_f32 (RTNE)
  return __builtin_bit_cast(unsigned short, h);
}
__device__ __forceinline__ float bf2f(unsigned short h) {
  union { unsigned int u; float f; } v; v.u = ((unsigned int)h) << 16;
  return v.f;
}
__device__ __forceinline__ f32x4 mfma16(bf16x8 a, bf16x8 b, f32x4 c) {
  return __builtin_amdgcn_mfma_f32_16x16x32_bf16(a, b, c, 0, 0, 0);
}
__device__ __forceinline__ void gl_lds16(const void* g, void* l) {
  __builtin_amdgcn_global_load_lds(
      (const __attribute__((address_space(1))) unsigned int*)g,
      (__attribute__((address_space(3))) unsigned int*)l, 16, 0, 0);
}
__device__ __forceinline__ void wait_lgkm0() {
  asm volatile("s_waitcnt lgkmcnt(0)" ::: "memory");
}

// ---------------- convert f32 -> bf16 ----------------
__global__ __launch_bounds__(256) void conv_bf16_kernel(const float* __restrict__ in,
                                                        unsigned short* __restrict__ out, int n4) {
  int e = blockIdx.x * 256 + threadIdx.x;
  if (e >= n4) return;
  float4 v = reinterpret_cast<const float4*>(in)[e];
  uint2 pk;
  pk.x = (unsigned int)f2bf(v.x) | ((unsigned int)f2bf(v.y) << 16);
  pk.y = (unsigned int)f2bf(v.z) | ((unsigned int)f2bf(v.w) << 16);
  reinterpret_cast<uint2*>(out)[e] = pk;
}

// ---------------- zero-fill bf16 region ----------------
__global__ __launch_bounds__(256) void zero_bf16_kernel(unsigned short* __restrict__ out, int n8) {
  int e = blockIdx.x * 256 + threadIdx.x;
  if (e >= n8) return;
  reinterpret_cast<uint4*>(out)[e] = uint4{0, 0, 0, 0};
}

// ------------- transpose+convert: in (K x N) f32 -> out (N x K) bf16 -------------
__global__ __launch_bounds__(256) void transpose_conv_kernel(const float* __restrict__ in,
                                                             unsigned short* __restrict__ out,
                                                             int K, int N) {
  __shared__ float t[32][33];
  int n0 = blockIdx.x * 32, k0 = blockIdx.y * 32;
  int tx = threadIdx.x & 31, ty = threadIdx.x >> 5;
#pragma unroll
  for (int i = 0; i < 4; i++) t[ty + i * 8][tx] = in[(size_t)(k0 + ty + i * 8) * N + n0 + tx];
  __syncthreads();
#pragma unroll
  for (int i = 0; i < 4; i++)
    out[(size_t)(n0 + ty + i * 8) * K + k0 + tx] = f2bf(t[tx][ty + i * 8]);
}

// ---- W_lambda_w (2048x16) -> wd_cat rows [2112,2128) bf16 ----
__global__ __launch_bounds__(256) void lamw_transpose_kernel(const float* __restrict__ in,
                                                             unsigned short* __restrict__ out) {
  int e = blockIdx.x * 256 + threadIdx.x;  // 16*2048
  if (e >= 16 * 2048) return;
  int k = e & 2047, n = e >> 11;
  out[(size_t)(2112 + n) * 2048 + k] = f2bf(in[(size_t)k * 16 + n]);
}

// ---------------- epilogue ----------------
// MODE 0: fp32 row-major C (stride N)
// MODE 4: fused down-proj: fp32 stride kTA; cols 0..1023 c_kv | 1024..2047 c_q
//         | 2048..2111 k_r | 2112..2127 lam_raw | >=2128 dropped
// MODE 5: fused UK|UV: gc<2048 -> k_all pack (XOR-swizzled d); else v_allT pack (XOR-swizzled l)
// MODE 6: fused UQ|QR: gc<4096 -> q_all pack (x kScale); else tmpB bf16 (stride 2048)
template <int MODE>
__device__ __forceinline__ void epi_store(void* dst, void* dst2, int gr, int gc, int N, float v) {
  if (MODE == 0) {
    reinterpret_cast<float*>(dst)[(size_t)gr * N + gc] = v;
  } else if (MODE == 4) {
    if (gc < kTA) reinterpret_cast<float*>(dst)[(size_t)gr * kTA + gc] = v;
  } else if (MODE == 5) {
    int bb = gr >> 11, l = gr & 2047;
    unsigned short hv = f2bf(v);
    if (gc < 2048) {
      int h = gc >> 7, d2 = gc & 127;
      int d2s = d2 ^ ((l & 7) << 3);  // K swizzle: 16B group XOR by row&7
      reinterpret_cast<unsigned short*>(dst)[((size_t)((bb * 16 + h) * 2048 + l)) * 192 + d2s] = hv;
    } else {
      int g2 = gc - 2048, h = g2 >> 7, d2 = g2 & 127;
      int ls = l ^ (((d2 >> 1) & 3) << 3);  // V swizzle: pos group XOR by (d>>1)&3
      reinterpret_cast<unsigned short*>(dst2)[((size_t)((bb * 16 + h) * 128 + d2)) * 2048 + ls] = hv;
    }
  } else if (MODE == 6) {
    int bb = gr >> 11, l = gr & 2047;
    if (gc < 4096) {
      int h2 = gc >> 7, d2 = gc & 127;
      reinterpret_cast<unsigned short*>(dst)[((size_t)((bb * 32 + h2) * 2048 + l)) * 192 + d2] =
          f2bf(v * kScale);
    } else {
      reinterpret_cast<unsigned short*>(dst2)[(size_t)gr * 2048 + (gc - 4096)] = f2bf(v);
    }
  }
}

// ---- m97-structure GEMM: C(MxN) = A(MxK) * Bt(NxK)^T, 128x128 tile, BK=32 ----
template <int MODE>
__global__ __launch_bounds__(256) void gemm128_kernel(const unsigned short* __restrict__ A,
                                                      const unsigned short* __restrict__ Bt,
                                                      void* __restrict__ dst, void* __restrict__ dst2,
                                                      int M, int N, int K) {
  __shared__ unsigned short lds_a[128 * 32];
  __shared__ unsigned short lds_b[128 * 32];
  int tid = threadIdx.x, lane = tid & 63, w = tid >> 6;
  int quad = lane >> 4, l16 = lane & 15;
  int wr = w >> 1, wc = w & 1;
  int mbase = blockIdx.y * 128, nbase = blockIdx.x * 128;
  f32x4 acc[4][4] = {};
  int srow0 = tid >> 2, skoff = (tid & 3) * 8;
  const size_t a_base = (size_t)(mbase + srow0) * K + skoff;
  const size_t b_base = (size_t)(nbase + srow0) * K + skoff;
  unsigned short* lba0 = &lds_a[(size_t)(w * 64) * 8];
  unsigned short* lba1 = &lds_a[(size_t)(256 + w * 64) * 8];
  unsigned short* lbb0 = &lds_b[(size_t)(w * 64) * 8];
  unsigned short* lbb1 = &lds_b[(size_t)(256 + w * 64) * 8];
  for (int k0 = 0; k0 < K; k0 += 32) {
    __syncthreads();
    gl_lds16(&A[a_base + k0], lba0);
    gl_lds16(&A[a_base + (size_t)64 * K + k0], lba1);
    gl_lds16(&Bt[b_base + k0], lbb0);
    gl_lds16(&Bt[b_base + (size_t)64 * K + k0], lbb1);
    __syncthreads();
    bf16x8 af[4], bfr[4];
#pragma unroll
    for (int i = 0; i < 4; i++) {
      af[i] = *reinterpret_cast<const bf16x8*>(&lds_a[(wr * 64 + i * 16 + l16) * 32 + quad * 8]);
      bfr[i] = *reinterpret_cast<const bf16x8*>(&lds_b[(wc * 64 + i * 16 + l16) * 32 + quad * 8]);
    }
#pragma unroll
    for (int i = 0; i < 4; i++)
#pragma unroll
      for (int j = 0; j < 4; j++) acc[i][j] = mfma16(af[i], bfr[j], acc[i][j]);
  }
#pragma unroll
  for (int i = 0; i < 4; i++)
#pragma unroll
    for (int j = 0; j < 4; j++)
#pragma unroll
      for (int r = 0; r < 4; r++) {
        int gr = mbase + wr * 64 + i * 16 + quad * 4 + r;
        int gc = nbase + wc * 64 + j * 16 + l16;
        epi_store<MODE>(dst, dst2, gr, gc, N, acc[i][j][r]);
      }
}

// ---------------- RMS norm: tmpAll fp32 (rows x kTA, col offset) -> out bf16 ----------------
__global__ __launch_bounds__(256) void rms_kernel(const float* __restrict__ in,
                                                  const float* __restrict__ w,
                                                  unsigned short* __restrict__ out, int colOff) {
  int row = blockIdx.x, tid = threadIdx.x;
  float4 v = reinterpret_cast<const float4*>(in + (size_t)row * kTA + colOff)[tid];
  float ss = v.x * v.x + v.y * v.y + v.z * v.z + v.w * v.w;
  ss += __shfl_xor(ss, 1); ss += __shfl_xor(ss, 2); ss += __shfl_xor(ss, 4);
  ss += __shfl_xor(ss, 8); ss += __shfl_xor(ss, 16); ss += __shfl_xor(ss, 32);
  __shared__ float red[4];
  if ((tid & 63) == 0) red[tid >> 6] = ss;
  __syncthreads();
  float tot = red[0] + red[1] + red[2] + red[3];
  float rs = rsqrtf(tot * (1.0f / kDC) + 1e-6f);
  float4 wv = reinterpret_cast<const float4*>(w)[tid];
  uint2 pk;
  pk.x = (unsigned int)f2bf(v.x * rs * wv.x) | ((unsigned int)f2bf(v.y * rs * wv.y) << 16);
  pk.y = (unsigned int)f2bf(v.z * rs * wv.z) | ((unsigned int)f2bf(v.w * rs * wv.w) << 16);
  reinterpret_cast<uint2*>(out)[(size_t)row * 256 + tid] = pk;
}

// ---------------- RoPE ----------------
__device__ __forceinline__ float rope_val(float x1, float x2, int j, int l) {
  int i = j & 31;
  float inv_freq = powf(10000.0f, -(float)i * (1.0f / 32.0f));
  float ang = (float)l * inv_freq;
  float cv = cosf(ang), sv = sinf(ang);
  float rot = (j < 32) ? -x2 : x2;
  return x1 * cv + rot * sv;
}

// q_r: tmpB bf16 (4096 x 2048, col = h2*64+j) -> q_all[..., 128+j], x kScale
__global__ __launch_bounds__(256) void rope_q_kernel(const unsigned short* __restrict__ qr_raw,
                                                     unsigned short* __restrict__ q_all) {
  size_t e = (size_t)blockIdx.x * 256 + threadIdx.x;  // 4096*32*64
  int j = (int)(e & 63);
  int h2 = (int)((e >> 6) & 31);
  int bl = (int)(e >> 11);
  int l = bl & 2047, b = bl >> 11;
  float x1 = bf2f(qr_raw[(size_t)bl * 2048 + h2 * 64 + j]);
  float x2 = bf2f(qr_raw[(size_t)bl * 2048 + h2 * 64 + (j ^ 32)]);
  float val = rope_val(x1, x2, j, l) * kScale;
  q_all[((size_t)((b * 32 + h2) * 2048 + l)) * 192 + 128 + j] = f2bf(val);
}

// k_r: tmpAll cols 2048..2111 -> k_all[..., 128 + (j^swz)] broadcast to 16 heads
__global__ __launch_bounds__(256) void rope_k_kernel(const float* __restrict__ tmpAll,
                                                     unsigned short* __restrict__ k_all) {
  size_t e = (size_t)blockIdx.x * 256 + threadIdx.x;  // 4096*64
  int j = (int)(e & 63);
  int bl = (int)(e >> 6);
  int l = bl & 2047, b = bl >> 11;
  float x1 = tmpAll[(size_t)bl * kTA + 2048 + j];
  float x2 = tmpAll[(size_t)bl * kTA + 2048 + (j ^ 32)];
  unsigned short hv = f2bf(rope_val(x1, x2, j, l));
  int js = j ^ ((l & 7) << 3);  // same 16B-group swizzle as MODE 5 K pack
#pragma unroll
  for (int h = 0; h < 16; h++)
    k_all[((size_t)((b * 16 + h) * 2048 + l)) * 192 + 128 + js] = hv;
}

// ---------------- lam = sigmoid(lam_raw + bias), from tmpAll cols 2112..2127 ----------------
__global__ __launch_bounds__(256) void lam_fin_kernel(const float* __restrict__ tmpAll,
                                                      const float* __restrict__ bl_,
                                                      float* __restrict__ lam) {
  int e = blockIdx.x * 256 + threadIdx.x;  // 4096*16
  if (e >= 4096 * 16) return;
  int n = e & 15, row = e >> 4;
  float z = tmpAll[(size_t)row * kTA + 2112 + n] + bl_[n];
  lam[e] = 1.f / (1.f + __expf(-z));
}

// ---------------- flash attention v3 (structure unchanged from R5) ----------------
__global__ __launch_bounds__(256, 3) void attn3_kernel(const unsigned short* __restrict__ q_all,
                                                       const unsigned short* __restrict__ k_all,
                                                       const unsigned short* __restrict__ v_allT,
                                                       unsigned short* __restrict__ attn_o) {
  __shared__ unsigned short lds_k[2][32 * 192];
  __shared__ unsigned short lds_v[2][128 * 32];
  __shared__ unsigned short lds_p[8 * 640];
  __shared__ unsigned short lds_ones[16 * 32];
  int qt = blockIdx.x, n = blockIdx.y, b = blockIdx.z;
  int tid = threadIdx.x, lane = tid & 63, w = tid >> 6, quad = lane >> 4, l16 = lane & 15;
  const unsigned short* k_head = k_all + ((size_t)(b * 16 + n) * 2048) * 192;
  const unsigned short* v_head = v_allT + ((size_t)(b * 16 + n) * 128) * 2048;
  const unsigned short* q0_row =
      q_all + ((size_t)(b * 32 + 2 * n) * 2048 + qt * 64 + w * 16 + l16) * 192;
  const unsigned short* q1_row = q0_row + (size_t)2048 * 192;

  bf16x8 qf0[6], qf1[6];
#pragma unroll
  for (int ks = 0; ks < 6; ks++) {
    qf0[ks] = *reinterpret_cast<const bf16x8*>(&q0_row[ks * 32 + quad * 8]);
    qf1[ks] = *reinterpret_cast<const bf16x8*>(&q1_row[ks * 32 + quad * 8]);
  }
  for (int idx = tid; idx < 512; idx += 256)
    lds_ones[idx] = (idx < 32) ? (unsigned short)0x3F80 : (unsigned short)0;

  f32x4 acc0[9] = {}, acc1[9] = {};
  unsigned short* pw0 = &lds_p[(w * 2 + 0) * 640];
  unsigned short* pw1 = &lds_p[(w * 2 + 1) * 640];
  int qlo = qt * 64 + w * 16;
  int nt = 2 * qt + 2;

  auto stage = [&](int pos0, int buf) {
    const unsigned short* kg = k_head + (size_t)pos0 * 192 + w * 1536 + lane * 8;
    unsigned short* kl = &lds_k[buf][w * 1536];
    gl_lds16(kg, kl);
    gl_lds16(kg + 512, kl + 512);
    gl_lds16(kg + 1024, kl + 1024);
    const unsigned short* vg =
        v_head + (size_t)(w * 32 + (lane >> 2)) * 2048 + pos0 + (lane & 3) * 8;
    unsigned short* vl = &lds_v[buf][w * 1024];
    gl_lds16(vg, vl);
    gl_lds16(vg + (size_t)16 * 2048, vl + 512);
  };

  stage(0, 0);
  for (int kt = 0; kt < nt; kt++) {
    int cur = kt & 1;
    int pos0 = kt * 32;
    __syncthreads();
    if (kt + 1 < nt) stage((kt + 1) * 32, cur ^ 1);
    if (pos0 <= qlo + 15) {
      const unsigned short* kb = &lds_k[cur][0];
      const unsigned short* vb = &lds_v[cur][0];
      bool needmask = (pos0 + 31 > qlo);
      int ksw = (l16 & 7) << 3;
      int vsw = (l16 >> 1) & 3;
#pragma unroll
      for (int j = 0; j < 2; j++) {
        f32x4 s0 = {}, s1 = {};
#pragma unroll
        for (int ks = 0; ks < 6; ks++) {
          bf16x8 bK = *reinterpret_cast<const bf16x8*>(
              &kb[(j * 16 + l16) * 192 + ((ks * 32 + quad * 8) ^ ksw)]);
          s0 = mfma16(qf0[ks], bK, s0);
          s1 = mfma16(qf1[ks], bK, s1);
        }
#pragma unroll
        for (int r = 0; r < 4; r++) {
          bool msk = needmask && (pos0 + j * 16 + l16 > qlo + quad * 4 + r);
          float p0 = msk ? 0.f : __expf(s0[r]);
          float p1 = msk ? 0.f : __expf(s1[r]);
          pw0[(quad * 4 + r) * 40 + j * 16 + l16] = f2bf(p0);
          pw1[(quad * 4 + r) * 40 + j * 16 + l16] = f2bf(p1);
        }
      }
      wait_lgkm0();  // wave-local: P ds_writes committed before P ds_reads
      bf16x8 pf0 = *reinterpret_cast<const bf16x8*>(&pw0[l16 * 40 + quad * 8]);
      bf16x8 pf1 = *reinterpret_cast<const bf16x8*>(&pw1[l16 * 40 + quad * 8]);
#pragma unroll
      for (int dt = 0; dt < 8; dt++) {
        bf16x8 vf = *reinterpret_cast<const bf16x8*>(
            &vb[(dt * 16 + l16) * 32 + ((quad ^ vsw) * 8)]);
        acc0[dt] = mfma16(pf0, vf, acc0[dt]);
        acc1[dt] = mfma16(pf1, vf, acc1[dt]);
      }
      bf16x8 vone = *reinterpret_cast<const bf16x8*>(&lds_ones[l16 * 32 + quad * 8]);
      acc0[8] = mfma16(pf0, vone, acc0[8]);
      acc1[8] = mfma16(pf1, vone, acc1[8]);
    }
  }
  unsigned short* o0 = attn_o + ((size_t)(b * 32 + 2 * n) * 2048 + qt * 64 + w * 16) * 128;
  unsigned short* o1 = o0 + (size_t)2048 * 128;
#pragma unroll
  for (int r = 0; r < 4; r++) {
    float li0 = __shfl(acc0[8][r], lane & 48);
    float li1 = __shfl(acc1[8][r], lane & 48);
    float inv0 = 1.f / li0, inv1 = 1.f / li1;
    int row = quad * 4 + r;
#pragma unroll
    for (int dt = 0; dt < 8; dt++) {
      o0[(size_t)row * 128 + dt * 16 + l16] = f2bf(acc0[dt][r] * inv0);
      o1[(size_t)row * 128 + dt * 16 + l16] = f2bf(acc1[dt][r] * inv1);
    }
  }
}

// ---------------- combine (x8 vectorized): attn1 - lam*attn2 -> bf16 [bl][n*128+d] ----------------
__global__ __launch_bounds__(256) void combine_kernel(const unsigned short* __restrict__ attn_o,
                                                      const float* __restrict__ lam,
                                                      unsigned short* __restrict__ out) {
  size_t e = (size_t)blockIdx.x * 256 + threadIdx.x;  // over 4096*2048/8
  int c8 = (int)(e & 255);
  int bl = (int)(e >> 8);
  int n = c8 >> 4, dd = (c8 & 15) * 8;
  int b = bl >> 11, l = bl & 2047;
  size_t base = ((size_t)((b * 32 + n * 2) * 2048 + l)) * 128 + dd;
  uint4 a1 = *reinterpret_cast<const uint4*>(attn_o + base);
  uint4 a2 = *reinterpret_cast<const uint4*>(attn_o + base + (size_t)2048 * 128);
  float lm = lam[(size_t)bl * 16 + n];
  unsigned int r[4];
  const unsigned int* p1 = &a1.x;
  const unsigned int* p2 = &a2.x;
#pragma unroll
  for (int i = 0; i < 4; i++) {
    float lo = bf2f((unsigned short)(p1[i] & 0xFFFF)) - lm * bf2f((unsigned short)(p2[i] & 0xFFFF));
    float hi = bf2f((unsigned short)(p1[i] >> 16)) - lm * bf2f((unsigned short)(p2[i] >> 16));
    r[i] = (unsigned int)f2bf(lo) | ((unsigned int)f2bf(hi) << 16);
  }
  *reinterpret_cast<uint4*>(out + e * 8) = uint4{r[0], r[1], r[2], r[3]};
}

}  // namespace

extern "C" void kernel_launch(void* const* d_in, const int* in_sizes, int n_in,
                              void* d_out, int out_size, void* d_ws, size_t ws_size,
                              hipStream_t stream) {
  const float* x      = (const float*)d_in[0];
  const float* W_DKV  = (const float*)d_in[1];
  const float* kvnw   = (const float*)d_in[2];
  const float* W_UK   = (const float*)d_in[3];
  const float* W_UV   = (const float*)d_in[4];
  const float* W_DQ   = (const float*)d_in[5];
  const float* qnw    = (const float*)d_in[6];
  const float* W_UQ   = (const float*)d_in[7];
  const float* W_QR   = (const float*)d_in[8];
  const float* W_KR   = (const float*)d_in[9];
  const float* W_lw   = (const float*)d_in[10];
  const float* W_lb   = (const float*)d_in[11];
  const float* W_out  = (const float*)d_in[12];
  float* out = (float*)d_out;

  // ---- workspace carve ----
  char* ws = (char*)d_ws;
  size_t off = 0;
  auto alloc = [&](size_t bytes) { char* p = ws + off; off += (bytes + 255) & ~(size_t)255; return p; };
  unsigned short* xb     = (unsigned short*)alloc((size_t)4096 * 2048 * 2);
  unsigned short* wd_cat = (unsigned short*)alloc((size_t)2176 * 2048 * 2);  // [DKV|DQ|KR|LAMW|pad] x K
  unsigned short* wu_cat = (unsigned short*)alloc((size_t)4096 * 1024 * 2);  // [UK|UV] x K
  unsigned short* wuqr   = (unsigned short*)alloc((size_t)6144 * 1024 * 2);  // [UQ|QR] x K
  unsigned short* wout   = (unsigned short*)alloc((size_t)2048 * 2048 * 2);
  unsigned short* ckv    = (unsigned short*)alloc((size_t)4096 * 1024 * 2);
  unsigned short* cq     = (unsigned short*)alloc((size_t)4096 * 1024 * 2);
  unsigned short* k_all  = (unsigned short*)alloc((size_t)2 * 16 * 2048 * 192 * 2);
  unsigned short* v_allT = (unsigned short*)alloc((size_t)2 * 16 * 128 * 2048 * 2);
  unsigned short* q_all  = (unsigned short*)alloc((size_t)2 * 32 * 2048 * 192 * 2);
  unsigned short* attn_o = (unsigned short*)alloc((size_t)2 * 32 * 2048 * 128 * 2);
  unsigned short* attn_b = (unsigned short*)alloc((size_t)4096 * 2048 * 2);
  float* lam             = (float*)alloc((size_t)4096 * 16 * 4);
  float* tmpAll          = (float*)alloc((size_t)4096 * kTA * 4);
  unsigned short* tmpB   = (unsigned short*)tmpAll;  // aliased: tmpAll consumed before GEMM<6>
  (void)ws_size; (void)in_sizes; (void)n_in; (void)out_size;

  // ---- convert x; weights transposed to NxK bf16, concatenated along N ----
  hipLaunchKernelGGL(conv_bf16_kernel, dim3(8192), dim3(256), 0, stream, x, xb, 2097152);
  hipLaunchKernelGGL(transpose_conv_kernel, dim3(32, 64), dim3(256), 0, stream, W_DKV, wd_cat, 2048, 1024);
  hipLaunchKernelGGL(transpose_conv_kernel, dim3(32, 64), dim3(256), 0, stream, W_DQ,
                     wd_cat + (size_t)1024 * 2048, 2048, 1024);
  hipLaunchKernelGGL(transpose_conv_kernel, dim3(2, 64), dim3(256), 0, stream, W_KR,
                     wd_cat + (size_t)2048 * 2048, 2048, 64);
  hipLaunchKernelGGL(lamw_transpose_kernel, dim3(128), dim3(256), 0, stream, W_lw, wd_cat);
  hipLaunchKernelGGL(zero_bf16_kernel, dim3(48), dim3(256), 0, stream,
                     wd_cat + (size_t)2128 * 2048, 12288);  // pad rows [2128,2176)
  hipLaunchKernelGGL(transpose_conv_kernel, dim3(64, 32), dim3(256), 0, stream, W_UK, wu_cat, 1024, 2048);
  hipLaunchKernelGGL(transpose_conv_kernel, dim3(64, 32), dim3(256), 0, stream, W_UV,
                     wu_cat + (size_t)2048 * 1024, 1024, 2048);
  hipLaunchKernelGGL(transpose_conv_kernel, dim3(128, 32), dim3(256), 0, stream, W_UQ, wuqr, 1024, 4096);
  hipLaunchKernelGGL(transpose_conv_kernel, dim3(64, 32), dim3(256), 0, stream, W_QR,
                     wuqr + (size_t)4096 * 1024, 1024, 2048);
  hipLaunchKernelGGL(transpose_conv_kernel, dim3(64, 64), dim3(256), 0, stream, W_out, wout, 2048, 2048);

  // ---- fused down-proj (DKV|DQ|KR|LAMW): 544 blocks ----
  hipLaunchKernelGGL(gemm128_kernel<4>, dim3(17, 32), dim3(256), 0, stream,
                     xb, wd_cat, tmpAll, (void*)nullptr, 4096, 2176, 2048);
  hipLaunchKernelGGL(rms_kernel, dim3(4096), dim3(256), 0, stream, tmpAll, kvnw, ckv, 0);
  hipLaunchKernelGGL(rms_kernel, dim3(4096), dim3(256), 0, stream, tmpAll, qnw, cq, 1024);
  hipLaunchKernelGGL(rope_k_kernel, dim3(1024), dim3(256), 0, stream, tmpAll, k_all);
  hipLaunchKernelGGL(lam_fin_kernel, dim3(256), dim3(256), 0, stream, tmpAll, W_lb, lam);

  // ---- fused up-projections: UK|UV (1024 blocks), UQ|QR (1536 blocks) ----
  hipLaunchKernelGGL(gemm128_kernel<5>, dim3(32, 32), dim3(256), 0, stream,
                     ckv, wu_cat, k_all, v_allT, 4096, 4096, 1024);
  hipLaunchKernelGGL(gemm128_kernel<6>, dim3(48, 32), dim3(256), 0, stream,
                     cq, wuqr, q_all, tmpB, 4096, 6144, 1024);  // tmpB clobbers tmpAll (consumed)
  hipLaunchKernelGGL(rope_q_kernel, dim3(32768), dim3(256), 0, stream, tmpB, q_all);

  // ---- attention v3 ----
  hipLaunchKernelGGL(attn3_kernel, dim3(32, 16, 2), dim3(256), 0, stream,
                     q_all, k_all, v_allT, attn_o);

  // ---- combine (x8) + output projection (512 blocks) ----
  hipLaunchKernelGGL(combine_kernel, dim3(4096), dim3(256), 0, stream, attn_o, lam, attn_b);
  hipLaunchKernelGGL(gemm128_kernel<0>, dim3(16, 32), dim3(256), 0, stream,
                     attn_b, wout, out, (void*)nullptr, 4096, 2048, 2048);
}